// Round 9
// baseline (451.432 us; speedup 1.0000x reference)
//
#include <hip/hip_runtime.h>
#include <hip/hip_bf16.h>
#include <math.h>

#define NUM_PM 254
#define NUM_VM 768
#define SEQQ   1024      // NUM_PM + NUM_VM + 2
#define NH     8
#define DD     256
#define DH     32
#define FF     1024
#define NB     8
#define MROWS  (NB*SEQQ) // 8192

typedef unsigned short u16;
typedef __attribute__((ext_vector_type(8))) short bf16x8;
typedef __attribute__((ext_vector_type(4))) float f32x4;

__device__ __forceinline__ float bf2f(u16 u){
    union { float f; unsigned int i; } c; c.i = ((unsigned int)u) << 16; return c.f;
}
__device__ __forceinline__ u16 f2bf(float f){
    union { float f; unsigned int u; } c; c.f = f;
    unsigned int r = c.u + 0x7FFFu + ((c.u >> 16) & 1u);   // RNE
    return (u16)(r >> 16);
}
__device__ __forceinline__ float gelu_tanh(float x){
    float x3 = x*x*x;
    float t = tanhf(0.7978845608028654f*(x + 0.044715f*x3));
    return 0.5f*x*(1.0f+t);
}

#define GLOAD16(gp, lp) __builtin_amdgcn_global_load_lds( \
    (const __attribute__((address_space(1))) void*)(gp), \
    (__attribute__((address_space(3))) void*)(lp), 16, 0, 0)

// ---------------------------------------------------------------- prologue:
// tcast (0..2303) | group build + out-zero (2304..2311) | embed+LN1 (2312..4359)
__global__ void prologue_kernel(const float* __restrict__ Wqkv, const float* __restrict__ Wo,
                                const float* __restrict__ W1,   const float* __restrict__ W2,
                                u16* __restrict__ wq, u16* __restrict__ wo,
                                u16* __restrict__ w1, u16* __restrict__ w2,
                                const int* __restrict__ rel, const unsigned char* __restrict__ mask,
                                int* __restrict__ kcnt, int* __restrict__ koff, int* __restrict__ kmem,
                                int* __restrict__ qcnt, int* __restrict__ qoff, int* __restrict__ qmem,
                                const float* __restrict__ vm_states,
                                const float* __restrict__ num_step,
                                const float* __restrict__ pm_states,
                                const float* __restrict__ pm_W, const float* __restrict__ pm_b,
                                const float* __restrict__ vm_W, const float* __restrict__ vm_b,
                                const float* __restrict__ g, const float* __restrict__ beta,
                                float* __restrict__ x, u16* __restrict__ h,
                                float* __restrict__ outz)
{
    __shared__ float t[32][33];
    __shared__ int cntS[256], offS[256], wsum4[4];
    __shared__ int qcntS[256], qoffS[256], qwsum4[4];
    int bid = blockIdx.x;
    int tid = threadIdx.x;
    if (bid < 2304){
        // ---- transpose-cast one 32x32 tile
        int id = bid;
        const float* in; u16* out; int K, N, layer, tile;
        if (id < 576)       { in=Wqkv; out=wq; K=256;  N=768;  layer=id/192; tile=id%192; }
        else if (id < 768)  { id-=576;  in=Wo; out=wo; K=256;  N=256;  layer=id/64;  tile=id%64;  }
        else if (id < 1536) { id-=768;  in=W1; out=w1; K=256;  N=1024; layer=id/256; tile=id%256; }
        else                { id-=1536; in=W2; out=w2; K=1024; N=256;  layer=id/256; tile=id%256; }
        int ntx = N/32;
        int n0 = (tile % ntx)*32, k0 = (tile / ntx)*32;
        size_t lofs = (size_t)layer * K * N;
        int tx = tid & 31, ty = tid >> 5;
        #pragma unroll
        for (int i=0;i<4;i++)
            t[ty + i*8][tx] = in[lofs + (size_t)(k0 + ty + i*8)*N + n0 + tx];
        __syncthreads();
        #pragma unroll
        for (int i=0;i<4;i++)
            out[lofs + (size_t)(n0 + ty + i*8)*K + k0 + tx] = f2bf(t[tx][ty + i*8]);
    } else if (bid < 2312){
        // ---- group build for batch b: two counting sorts by code
        //      keys  (kmem): middle tokens, masked excluded
        //      query (qmem): all middle tokens
        int b = bid - 2304;
        cntS[tid] = 0; qcntS[tid] = 0;
        __syncthreads();
        int myc[4], myp[4], myqp[4];
        bool mym[4];
        #pragma unroll
        for (int si=0; si<4; si++){
            int s = si*256 + tid;
            bool mid = (s != 0) && (s != SEQQ-1);
            myc[si] = -1; mym[si] = false;
            if (mid){
                int cc = rel[b*(SEQQ-2) + s-1];
                myc[si] = cc;
                bool masked = (s >= 1+NUM_PM) && mask[b*NUM_VM + (s-1-NUM_PM)];
                mym[si] = masked;
                myqp[si] = atomicAdd(&qcntS[cc], 1);
                if (!masked) myp[si] = atomicAdd(&cntS[cc], 1);
            }
        }
        __syncthreads();
        {
            int v = cntS[tid], qv = qcntS[tid];
            int incl = v, qincl = qv;
            #pragma unroll
            for (int d=1; d<64; d<<=1){
                int n  = __shfl_up(incl, d);
                int qn = __shfl_up(qincl, d);
                if ((tid & 63) >= d){ incl += n; qincl += qn; }
            }
            offS[tid]  = incl - v;
            qoffS[tid] = qincl - qv;
            if ((tid & 63) == 63){ wsum4[tid>>6] = incl; qwsum4[tid>>6] = qincl; }
        }
        __syncthreads();
        {
            int w = tid >> 6, base = 0, qbase = 0;
            #pragma unroll
            for (int i=0;i<4;i++) if (i < w){ base += wsum4[i]; qbase += qwsum4[i]; }
            offS[tid] += base;
            qoffS[tid] += qbase;
        }
        __syncthreads();
        #pragma unroll
        for (int si=0; si<4; si++){
            if (myc[si] >= 0){
                int s = si*256 + tid;
                if (!mym[si]) kmem[b*SEQQ + offS[myc[si]] + myp[si]] = s;
                qmem[b*SEQQ + qoffS[myc[si]] + myqp[si]] = s;
            }
        }
        kcnt[b*256 + tid] = cntS[tid];
        koff[b*256 + tid] = offS[tid];
        qcnt[b*256 + tid] = qcntS[tid];
        qoff[b*256 + tid] = qoffS[tid];
        // zero the 769 outputs of this batch (head uses atomicAdd)
        #pragma unroll
        for (int si=0; si<4; si++){
            int idx = si*256 + tid;
            if (idx < 769) outz[b*769 + idx] = 0.f;
        }
    } else {
        // ---- embed + LN1(layer0): wave per row
        int row = (bid - 2312)*4 + (tid>>6);
        int lane = tid & 63;
        int b = row >> 10, s = row & 1023;
        int col = lane*4;
        float4 out;
        if (s == 0){
            float v = num_step[b]; out = (float4){v,v,v,v};
        } else if (s == SEQQ-1){
            out = (float4){-1.f,-1.f,-1.f,-1.f};
        } else {
            const float* in; const float* W; const float* bias;
            if (s <= NUM_PM){ in = pm_states + (size_t)(b*NUM_PM + s-1)*16; W = pm_W; bias = pm_b; }
            else            { in = vm_states + (size_t)(b*NUM_VM + (s-1-NUM_PM))*16; W = vm_W; bias = vm_b; }
            float4 i0 = *(const float4*)in,      i1 = *(const float4*)(in+4);
            float4 i2 = *(const float4*)(in+8),  i3 = *(const float4*)(in+12);
            float in16[16] = {i0.x,i0.y,i0.z,i0.w, i1.x,i1.y,i1.z,i1.w,
                              i2.x,i2.y,i2.z,i2.w, i3.x,i3.y,i3.z,i3.w};
            out = *(const float4*)&bias[col];
            #pragma unroll
            for (int k=0;k<16;k++){
                float4 w4 = *(const float4*)&W[k*DD + col];
                out.x = fmaf(in16[k], w4.x, out.x);
                out.y = fmaf(in16[k], w4.y, out.y);
                out.z = fmaf(in16[k], w4.z, out.z);
                out.w = fmaf(in16[k], w4.w, out.w);
            }
        }
        *(float4*)&x[(size_t)row*DD + col] = out;
        float s1 = out.x+out.y+out.z+out.w;
        float s2 = fmaf(out.x,out.x, fmaf(out.y,out.y, fmaf(out.z,out.z, out.w*out.w)));
        #pragma unroll
        for (int off=1; off<64; off<<=1){ s1 += __shfl_xor(s1,off); s2 += __shfl_xor(s2,off); }
        float m    = s1*(1.0f/DD);
        float var  = s2*(1.0f/DD) - m*m;
        float rstd = rsqrtf(var + 1e-5f);
        float4 g4 = *(const float4*)&g[col];
        float4 b4 = *(const float4*)&beta[col];
        short4 o;
        o.x = (short)f2bf((out.x-m)*rstd*g4.x + b4.x);
        o.y = (short)f2bf((out.y-m)*rstd*g4.y + b4.y);
        o.z = (short)f2bf((out.z-m)*rstd*g4.z + b4.z);
        o.w = (short)f2bf((out.w-m)*rstd*g4.w + b4.w);
        *(short4*)&h[(size_t)row*DD + col] = o;
    }
}

// ---------------------------------------------------------------- layernorm: wave per row, f32 in -> bf16 out
__global__ void ln_kernel(const float* __restrict__ x, const float* __restrict__ g,
                          const float* __restrict__ bta, u16* __restrict__ out)
{
    int row = blockIdx.x*4 + (threadIdx.x>>6);
    int lane = threadIdx.x & 63;
    const float4 v = *(const float4*)&x[(size_t)row*DD + lane*4];
    float s1 = v.x+v.y+v.z+v.w;
    float s2 = fmaf(v.x,v.x, fmaf(v.y,v.y, fmaf(v.z,v.z, v.w*v.w)));
    #pragma unroll
    for (int off=1; off<64; off<<=1){ s1 += __shfl_xor(s1,off); s2 += __shfl_xor(s2,off); }
    float m    = s1*(1.0f/DD);
    float var  = s2*(1.0f/DD) - m*m;
    float rstd = rsqrtf(var + 1e-5f);
    float4 g4 = *(const float4*)&g[lane*4];
    float4 b4 = *(const float4*)&bta[lane*4];
    short4 o;
    o.x = (short)f2bf((v.x-m)*rstd*g4.x + b4.x);
    o.y = (short)f2bf((v.y-m)*rstd*g4.y + b4.y);
    o.z = (short)f2bf((v.z-m)*rstd*g4.z + b4.z);
    o.w = (short)f2bf((v.w-m)*rstd*g4.w + b4.w);
    *(short4*)&out[(size_t)row*DD + lane*4] = o;
}

// ---------------------------------------------------------------- MFMA GEMM 64x128, dbuf: C bf16 = A@Bt^T + bias   (QKV)
__launch_bounds__(256)
__global__ void qgemm_kernel(const u16* __restrict__ A, const u16* __restrict__ Bt,
                             const float* __restrict__ bias, u16* __restrict__ C,
                             int N, int K)
{
    __shared__ u16 As[2][64][32];
    __shared__ u16 Bs[2][128][32];
    int tid = threadIdx.x;
    int wid = tid >> 6, lane = tid & 63;
    int wr = wid >> 1, wc = wid & 1;            // wave tile 32x64
    int row0 = blockIdx.y*64, col0 = blockIdx.x*128;
    int l15 = lane & 15, lh = lane >> 4;

    const u16* Ag = A  + (size_t)(row0 + wid*16 + (lane>>2))*K + (lane&3)*8;
    const u16* Bg = Bt + (size_t)(col0 + wid*32 + (lane>>2))*K + (lane&3)*8;

#define STAGE_Q(buf, k0) do{ \
    GLOAD16(Ag + (k0),          &As[buf][wid*16][0]);    \
    GLOAD16(Bg + (k0),          &Bs[buf][wid*32][0]);    \
    GLOAD16(Bg + (k0) + 16*K,   &Bs[buf][wid*32+16][0]); }while(0)

    f32x4 acc[2][4] = {};
    int nk = K >> 5;
    STAGE_Q(0, 0);
    __syncthreads();
    for (int kt = 0; kt < nk; kt++){
        int cur = kt & 1;
        if (kt+1 < nk) STAGE_Q(cur^1, (kt+1)*32);
        bf16x8 af[2], bfv[4];
        #pragma unroll
        for (int i=0;i<2;i++)
            af[i] = *(const bf16x8*)&As[cur][wr*32 + i*16 + l15][lh*8];
        #pragma unroll
        for (int j=0;j<4;j++)
            bfv[j] = *(const bf16x8*)&Bs[cur][wc*64 + j*16 + l15][lh*8];
        #pragma unroll
        for (int i=0;i<2;i++)
            #pragma unroll
            for (int j=0;j<4;j++)
                acc[i][j] = __builtin_amdgcn_mfma_f32_16x16x32_bf16(af[i], bfv[j], acc[i][j], 0,0,0);
        __syncthreads();
    }
#undef STAGE_Q

    #pragma unroll
    for (int i=0;i<2;i++){
        #pragma unroll
        for (int j=0;j<4;j++){
            int col = col0 + wc*64 + j*16 + l15;
            float bb = bias[col];
            #pragma unroll
            for (int r=0;r<4;r++){
                int row = row0 + wr*32 + i*16 + lh*4 + r;
                C[(size_t)row*N + col] = f2bf(acc[i][j][r] + bb);
            }
        }
    }
}

// ---------------------------------------------------------------- MFMA GEMM 128x128, dbuf: C bf16 = gelu(A@Bt^T + bias)   (FF1)
__launch_bounds__(256)
__global__ void mgemm_kernel(const u16* __restrict__ A, const u16* __restrict__ Bt,
                             const float* __restrict__ bias, u16* __restrict__ C,
                             int N, int K)
{
    __shared__ u16 As[2][128][32];
    __shared__ u16 Bs[2][128][32];
    int tid = threadIdx.x;
    int wid = tid >> 6, lane = tid & 63;
    int wr = wid >> 1, wc = wid & 1;
    int row0 = blockIdx.y*128, col0 = blockIdx.x*128;
    int l15 = lane & 15, lh = lane >> 4;

    const u16* Ag = A  + (size_t)(row0 + wid*32 + (lane>>2))*K + (lane&3)*8;
    const u16* Bg = Bt + (size_t)(col0 + wid*32 + (lane>>2))*K + (lane&3)*8;

#define STAGE_M(buf, k0) do{ \
    GLOAD16(Ag + (k0),          &As[buf][wid*32][0]);    \
    GLOAD16(Ag + (k0) + 16*K,   &As[buf][wid*32+16][0]); \
    GLOAD16(Bg + (k0),          &Bs[buf][wid*32][0]);    \
    GLOAD16(Bg + (k0) + 16*K,   &Bs[buf][wid*32+16][0]); }while(0)

    f32x4 acc[4][4] = {};
    int nk = K >> 5;
    STAGE_M(0, 0);
    __syncthreads();
    for (int kt = 0; kt < nk; kt++){
        int cur = kt & 1;
        if (kt+1 < nk) STAGE_M(cur^1, (kt+1)*32);
        bf16x8 af[4], bfv[4];
        #pragma unroll
        for (int f=0; f<4; f++){
            af[f]  = *(const bf16x8*)&As[cur][wr*64 + f*16 + l15][lh*8];
            bfv[f] = *(const bf16x8*)&Bs[cur][wc*64 + f*16 + l15][lh*8];
        }
        #pragma unroll
        for (int i=0;i<4;i++)
            #pragma unroll
            for (int j=0;j<4;j++)
                acc[i][j] = __builtin_amdgcn_mfma_f32_16x16x32_bf16(af[i], bfv[j], acc[i][j], 0,0,0);
        __syncthreads();
    }
#undef STAGE_M

    #pragma unroll
    for (int i=0;i<4;i++){
        #pragma unroll
        for (int j=0;j<4;j++){
            int col = col0 + wc*64 + j*16 + l15;
            float bb = bias[col];
            #pragma unroll
            for (int r=0;r<4;r++){
                int row = row0 + wr*64 + i*16 + lh*4 + r;
                C[(size_t)row*N + col] = f2bf(gelu_tanh(acc[i][j][r] + bb));
            }
        }
    }
}

// ---------------------------------------------------------------- MFMA GEMM 64x64, dbuf: x[M,256] += A@Bt^T + bias  (+head)
template<int HEAD>
__launch_bounds__(256)
__global__ void mgemm64_kernel(const u16* __restrict__ A, const u16* __restrict__ Bt,
                               const float* __restrict__ bias, float* __restrict__ x,
                               const float* __restrict__ out_W, const float* __restrict__ out_b,
                               const float* __restrict__ crit_W, const float* __restrict__ crit_b,
                               float* __restrict__ out, int K)
{
    __shared__ u16 As[2][64][32];
    __shared__ u16 Bs[2][64][32];
    int tid = threadIdx.x;
    int wid = tid >> 6, lane = tid & 63;
    int wr = wid >> 1, wc = wid & 1;            // wave tile 32x32
    int row0 = blockIdx.y*64, col0 = blockIdx.x*64;
    int l15 = lane & 15, lh = lane >> 4;

    const u16* Ag = A  + (size_t)(row0 + wid*16 + (lane>>2))*K + (lane&3)*8;
    const u16* Bg = Bt + (size_t)(col0 + wid*16 + (lane>>2))*K + (lane&3)*8;

#define STAGE_S(buf, k0) do{ \
    GLOAD16(Ag + (k0), &As[buf][wid*16][0]); \
    GLOAD16(Bg + (k0), &Bs[buf][wid*16][0]); }while(0)

    f32x4 acc[2][2] = {};
    int nk = K >> 5;
    STAGE_S(0, 0);
    __syncthreads();
    for (int kt = 0; kt < nk; kt++){
        int cur = kt & 1;
        if (kt+1 < nk) STAGE_S(cur^1, (kt+1)*32);
        bf16x8 af[2], bfv[2];
        #pragma unroll
        for (int i=0;i<2;i++)
            af[i] = *(const bf16x8*)&As[cur][wr*32 + i*16 + l15][lh*8];
        #pragma unroll
        for (int j=0;j<2;j++)
            bfv[j] = *(const bf16x8*)&Bs[cur][wc*32 + j*16 + l15][lh*8];
        #pragma unroll
        for (int i=0;i<2;i++)
            #pragma unroll
            for (int j=0;j<2;j++)
                acc[i][j] = __builtin_amdgcn_mfma_f32_16x16x32_bf16(af[i], bfv[j], acc[i][j], 0,0,0);
        __syncthreads();
    }
#undef STAGE_S

    #pragma unroll
    for (int i=0;i<2;i++){
        #pragma unroll
        for (int r=0;r<4;r++){
            int row = row0 + wr*32 + i*16 + lh*4 + r;
            float hp = 0.f;
            int s = row & 1023;
            #pragma unroll
            for (int j=0;j<2;j++){
                int col = col0 + wc*32 + j*16 + l15;
                size_t idx = (size_t)row*DD + col;
                float v = acc[i][j][r] + bias[col] + x[idx];
                x[idx] = v;
                if (HEAD){
                    float w = (s == 1023) ? crit_W[col] : out_W[col];
                    hp = fmaf(v, w, hp);
                }
            }
            if (HEAD && s >= 1 + NUM_PM){
                hp += __shfl_xor(hp, 1);
                hp += __shfl_xor(hp, 2);
                hp += __shfl_xor(hp, 4);
                hp += __shfl_xor(hp, 8);
                if (l15 == 0){
                    int b = row >> 10;
                    int jj = (s == 1023) ? 768 : (s - (1 + NUM_PM));
                    float add = hp;
                    if (blockIdx.x == 0 && wc == 0)
                        add += (s == 1023) ? crit_b[0] : out_b[0];
                    atomicAdd(&out[b*769 + jj], add);
                }
            }
        }
    }
}

// ---------------------------------------------------------------- group-centric attention: one wave per (b,code) group
// lane = h*8+i holds dims [lane*4, lane*4+4) of the 256-dim head-concat row
__launch_bounds__(256)
__global__ void gattn_kernel(const u16* __restrict__ qkv,
                             const int* __restrict__ kcnt, const int* __restrict__ koff,
                             const int* __restrict__ kmem,
                             const int* __restrict__ qcnt, const int* __restrict__ qoff,
                             const int* __restrict__ qmem,
                             u16* __restrict__ o)
{
    int gidx = blockIdx.x*4 + (threadIdx.x >> 6);
    int lane = threadIdx.x & 63;
    const float scale = 0.17677669529663687f;       // 1/sqrt(32)

    if (gidx >= NB*256){
        // specials: s=0 and s=SEQQ-1 attend only to themselves -> o = V[s]
        int idx = gidx - NB*256;                    // 0..15
        int b = idx >> 1, s = (idx & 1) ? (SEQQ-1) : 0;
        const u16* vrow = qkv + (size_t)(b*SEQQ + s)*768 + 512 + lane*4;
        *(short4*)(o + (size_t)(b*SEQQ + s)*DD + lane*4) = *(const short4*)vrow;
        return;
    }
    int b = gidx >> 8, c = gidx & 255;
    int gq = qcnt[b*256 + c];
    if (gq == 0) return;
    int gk = kcnt[b*256 + c];
    const int* klist = kmem + b*SEQQ + koff[b*256 + c];
    const int* qlist = qmem + b*SEQQ + qoff[b*256 + c];

    if (gk == 0){
        // no valid keys (only possible with masking) — emit zeros
        for (int i=0;i<gq;i++){
            int s = qlist[i];
            short4 z = {0,0,0,0};
            *(short4*)(o + (size_t)(b*SEQQ + s)*DD + lane*4) = z;
        }
        return;
    }

    if (gk <= 8){
        // load all K,V rows of the group into registers (static-indexed)
        float4 kr[8], vr[8];
        #pragma unroll
        for (int j=0;j<8;j++){
            int mi = klist[(j < gk) ? j : 0];
            const u16* kb = qkv + (size_t)(b*SEQQ + mi)*768 + 256 + lane*4;
            short4 k4 = *(const short4*)kb;
            short4 v4 = *(const short4*)(kb + 256);
            kr[j] = (float4){bf2f((u16)k4.x), bf2f((u16)k4.y), bf2f((u16)k4.z), bf2f((u16)k4.w)};
            vr[j] = (float4){bf2f((u16)v4.x), bf2f((u16)v4.y), bf2f((u16)v4.z), bf2f((u16)v4.w)};
        }
        for (int i=0;i<gq;i++){
            int s = qlist[i];
            const u16* qb = qkv + (size_t)(b*SEQQ + s)*768 + lane*4;
            short4 q4i = *(const short4*)qb;
            float qx = bf2f((u16)q4i.x)*scale, qy = bf2f((u16)q4i.y)*scale,
                  qz = bf2f((u16)q4i.z)*scale, qw = bf2f((u16)q4i.w)*scale;
            float sc[8];
            #pragma unroll
            for (int j=0;j<8;j++){
                float d = qx*kr[j].x + qy*kr[j].y + qz*kr[j].z + qw*kr[j].w;
                d += __shfl_xor(d, 1);
                d += __shfl_xor(d, 2);
                d += __shfl_xor(d, 4);
                sc[j] = d;
            }
            float m = -1e30f;
            #pragma unroll
            for (int j=0;j<8;j++) if (j < gk) m = fmaxf(m, sc[j]);
            float l = 0.f;
            float ax=0.f, ay=0.f, az=0.f, aw=0.f;
            #pragma unroll
            for (int j=0;j<8;j++){
                if (j < gk){
                    float p = __expf(sc[j] - m);
                    l += p;
                    ax = fmaf(p, vr[j].x, ax);
                    ay = fmaf(p, vr[j].y, ay);
                    az = fmaf(p, vr[j].z, az);
                    aw = fmaf(p, vr[j].w, aw);
                }
            }
            float inv = 1.0f/l;
            short4 outv;
            outv.x = (short)f2bf(ax*inv); outv.y = (short)f2bf(ay*inv);
            outv.z = (short)f2bf(az*inv); outv.w = (short)f2bf(aw*inv);
            *(short4*)(o + (size_t)(b*SEQQ + s)*DD + lane*4) = outv;
        }
    } else {
        // rare large groups: per-query gathered online softmax (chunked)
        for (int i=0;i<gq;i++){
            int s = qlist[i];
            const u16* qb = qkv + (size_t)(b*SEQQ + s)*768 + lane*4;
            short4 q4i = *(const short4*)qb;
            float qx = bf2f((u16)q4i.x)*scale, qy = bf2f((u16)q4i.y)*scale,
                  qz = bf2f((u16)q4i.z)*scale, qw = bf2f((u16)q4i.w)*scale;
            float m_run = -1e30f, l_run = 0.f;
            float ax=0.f, ay=0.f, az=0.f, aw=0.f;
            for (int j0 = 0; j0 < gk; j0 += 4){
                short4 k4[4], v4[4];
                #pragma unroll
                for (int k=0;k<4;k++){
                    int jj = j0 + k; jj = (jj < gk) ? jj : (gk-1);
                    int mi = klist[jj];
                    const u16* kb = qkv + (size_t)(b*SEQQ + mi)*768 + 256 + lane*4;
                    k4[k] = *(const short4*)kb;
                    v4[k] = *(const short4*)(kb + 256);
                }
                #pragma unroll
                for (int k=0;k<4;k++){
                    if (j0 + k < gk){
                        float d = qx*bf2f((u16)k4[k].x) + qy*bf2f((u16)k4[k].y)
                                + qz*bf2f((u16)k4[k].z) + qw*bf2f((u16)k4[k].w);
                        d += __shfl_xor(d, 1);
                        d += __shfl_xor(d, 2);
                        d += __shfl_xor(d, 4);
                        float mn = fmaxf(m_run, d);
                        float corr = __expf(m_run - mn);
                        float p = __expf(d - mn);
                        l_run = l_run*corr + p;
                        ax = ax*corr + p*bf2f((u16)v4[k].x);
                        ay = ay*corr + p*bf2f((u16)v4[k].y);
                        az = az*corr + p*bf2f((u16)v4[k].z);
                        aw = aw*corr + p*bf2f((u16)v4[k].w);
                        m_run = mn;
                    }
                }
            }
            float inv = 1.0f/l_run;
            short4 outv;
            outv.x = (short)f2bf(ax*inv); outv.y = (short)f2bf(ay*inv);
            outv.z = (short)f2bf(az*inv); outv.w = (short)f2bf(aw*inv);
            *(short4*)(o + (size_t)(b*SEQQ + s)*DD + lane*4) = outv;
        }
    }
}

// ---------------------------------------------------------------- launch
extern "C" void kernel_launch(void* const* d_in, const int* in_sizes, int n_in,
                              void* d_out, int out_size, void* d_ws, size_t ws_size,
                              hipStream_t stream)
{
    const float* vm_states = (const float*)d_in[0];
    const float* num_step  = (const float*)d_in[1];
    const float* pm_states = (const float*)d_in[2];
    const int*   rel       = (const int*)d_in[3];
    const unsigned char* mask = (const unsigned char*)d_in[4];
    const float* pm_W = (const float*)d_in[5];
    const float* pm_b = (const float*)d_in[6];
    const float* vm_W = (const float*)d_in[7];
    const float* vm_b = (const float*)d_in[8];
    const float* Wqkv = (const float*)d_in[9];
    const float* bqkv = (const float*)d_in[10];
    const float* Wo   = (const float*)d_in[11];
    const float* bo   = (const float*)d_in[12];
    const float* ln1g = (const float*)d_in[13];
    const float* ln1b = (const float*)d_in[14];
    const float* ln2g = (const float*)d_in[15];
    const float* ln2b = (const float*)d_in[16];
    const float* W1   = (const float*)d_in[17];
    const float* b1   = (const float*)d_in[18];
    const float* W2   = (const float*)d_in[19];
    const float* b2   = (const float*)d_in[20];
    const float* out_W = (const float*)d_in[21];
    const float* out_b = (const float*)d_in[22];
    const float* crit_W = (const float*)d_in[23];
    const float* crit_b = (const float*)d_in[24];

    char* ws = (char*)d_ws;
    const size_t MB = 1024*1024;
    float* x    = (float*)(ws);                      // [8192][256] f32   :  0..8 MB
    u16*   hbuf = (u16*)(ws + 8*MB);                 // [8192][256] bf16  :  8..12
    u16*   aout = (u16*)(ws + 12*MB);                // [8192][256] bf16  : 12..16
    u16*   qkv  = (u16*)(ws + 16*MB);                // [8192][768] bf16  : 16..28
    u16*   ff1  = (u16*)(ws + 28*MB);                // [8192][1024] bf16 : 28..44
    u16*   wq   = (u16*)(ws + 44*MB);                // [3][768][256]
    u16*   wo   = wq + (size_t)3*768*256;            // [3][256][256]
    u16*   w1   = wo + (size_t)3*256*256;            // [3][1024][256]
    u16*   w2   = w1 + (size_t)3*1024*256;           // [3][256][1024]
    int*   kcnt = (int*)(ws + 50*MB);                // [8][256]
    int*   koff = kcnt + NB*256;
    int*   kmem = koff + NB*256;                     // [8][1024]
    int*   qcnt = kmem + NB*SEQQ;                    // [8][256]
    int*   qoff = qcnt + NB*256;
    int*   qmem = qoff + NB*256;                     // [8][1024]

    prologue_kernel<<<4360, 256, 0, stream>>>(Wqkv, Wo, W1, W2, wq, wo, w1, w2,
                                              rel, mask, kcnt, koff, kmem, qcnt, qoff, qmem,
                                              vm_states, num_step, pm_states,
                                              pm_W, pm_b, vm_W, vm_b,
                                              ln1g, ln1b, x, hbuf, (float*)d_out);
    for (int i=0;i<3;i++){
        qgemm_kernel<<<dim3(768/128, MROWS/64),256,0,stream>>>(
            hbuf, wq + (size_t)i*768*256, bqkv + i*768, qkv, 768, 256);
        gattn_kernel<<<(NB*256 + 16)/4, 256, 0, stream>>>(
            qkv, kcnt, koff, kmem, qcnt, qoff, qmem, aout);
        mgemm64_kernel<0><<<dim3(256/64, MROWS/64),256,0,stream>>>(
            aout, wo + (size_t)i*256*256, bo + i*DD, x,
            nullptr, nullptr, nullptr, nullptr, nullptr, 256);
        ln_kernel<<<MROWS/4,256,0,stream>>>(x, ln2g + i*DD, ln2b + i*DD, hbuf);
        mgemm_kernel<<<dim3(1024/128, MROWS/128),256,0,stream>>>(
            hbuf, w1 + (size_t)i*1024*256, b1 + i*FF, ff1, 1024, 256);
        if (i < 2){
            mgemm64_kernel<0><<<dim3(256/64, MROWS/64),256,0,stream>>>(
                ff1, w2 + (size_t)i*256*1024, b2 + i*DD, x,
                nullptr, nullptr, nullptr, nullptr, nullptr, 1024);
            ln_kernel<<<MROWS/4,256,0,stream>>>(x, ln1g + (i+1)*DD, ln1b + (i+1)*DD, hbuf);
        } else {
            mgemm64_kernel<1><<<dim3(256/64, MROWS/64),256,0,stream>>>(
                ff1, w2 + (size_t)i*256*1024, b2 + i*DD, x,
                out_W, out_b, crit_W, crit_b, (float*)d_out, 1024);
        }
    }
}

// Round 10
// 332.352 us; speedup vs baseline: 1.3583x; 1.3583x over previous
//
#include <hip/hip_runtime.h>
#include <hip/hip_bf16.h>
#include <math.h>

#define NUM_PM 254
#define NUM_VM 768
#define SEQQ   1024      // NUM_PM + NUM_VM + 2
#define NH     8
#define DD     256
#define DH     32
#define FF     1024
#define NB     8
#define MROWS  (NB*SEQQ) // 8192

typedef unsigned short u16;
typedef __attribute__((ext_vector_type(8))) short bf16x8;
typedef __attribute__((ext_vector_type(4))) float f32x4;

__device__ __forceinline__ float bf2f(u16 u){
    union { float f; unsigned int i; } c; c.i = ((unsigned int)u) << 16; return c.f;
}
__device__ __forceinline__ u16 f2bf(float f){
    union { float f; unsigned int u; } c; c.f = f;
    unsigned int r = c.u + 0x7FFFu + ((c.u >> 16) & 1u);   // RNE
    return (u16)(r >> 16);
}
__device__ __forceinline__ float gelu_tanh(float x){
    float x3 = x*x*x;
    float t = tanhf(0.7978845608028654f*(x + 0.044715f*x3));
    return 0.5f*x*(1.0f+t);
}

#define GLOAD16(gp, lp) __builtin_amdgcn_global_load_lds( \
    (const __attribute__((address_space(1))) void*)(gp), \
    (__attribute__((address_space(3))) void*)(lp), 16, 0, 0)

// ---------------------------------------------------------------- prologue:
// tcast (0..2303) | group build + pq tables + out-zero (2304..2311) | embed+LN1 (2312..4359)
__global__ void prologue_kernel(const float* __restrict__ Wqkv, const float* __restrict__ Wo,
                                const float* __restrict__ W1,   const float* __restrict__ W2,
                                u16* __restrict__ wq, u16* __restrict__ wo,
                                u16* __restrict__ w1, u16* __restrict__ w2,
                                const int* __restrict__ rel, const unsigned char* __restrict__ mask,
                                int* __restrict__ kcnt, int* __restrict__ koff, int* __restrict__ kmem,
                                int* __restrict__ pcnt, int* __restrict__ poff, int* __restrict__ pmem,
                                const float* __restrict__ vm_states,
                                const float* __restrict__ num_step,
                                const float* __restrict__ pm_states,
                                const float* __restrict__ pm_W, const float* __restrict__ pm_b,
                                const float* __restrict__ vm_W, const float* __restrict__ vm_b,
                                const float* __restrict__ g, const float* __restrict__ beta,
                                float* __restrict__ x, u16* __restrict__ h,
                                float* __restrict__ outz)
{
    __shared__ float t[32][33];
    __shared__ int cntS[256], offS[256], wsum4[4];
    __shared__ int memS[1040];
    int bid = blockIdx.x;
    int tid = threadIdx.x;
    if (bid < 2304){
        // ---- transpose-cast one 32x32 tile
        int id = bid;
        const float* in; u16* out; int K, N, layer, tile;
        if (id < 576)       { in=Wqkv; out=wq; K=256;  N=768;  layer=id/192; tile=id%192; }
        else if (id < 768)  { id-=576;  in=Wo; out=wo; K=256;  N=256;  layer=id/64;  tile=id%64;  }
        else if (id < 1536) { id-=768;  in=W1; out=w1; K=256;  N=1024; layer=id/256; tile=id%256; }
        else                { id-=1536; in=W2; out=w2; K=1024; N=256;  layer=id/256; tile=id%256; }
        int ntx = N/32;
        int n0 = (tile % ntx)*32, k0 = (tile / ntx)*32;
        size_t lofs = (size_t)layer * K * N;
        int tx = tid & 31, ty = tid >> 5;
        #pragma unroll
        for (int i=0;i<4;i++)
            t[ty + i*8][tx] = in[lofs + (size_t)(k0 + ty + i*8)*N + n0 + tx];
        __syncthreads();
        #pragma unroll
        for (int i=0;i<4;i++)
            out[lofs + (size_t)(n0 + ty + i*8)*K + k0 + tx] = f2bf(t[tx][ty + i*8]);
    } else if (bid < 2312){
        // ---- group build for batch b (counting sort of valid keys by code) + pq tables
        int b = bid - 2304;
        cntS[tid] = 0;
        __syncthreads();
        int myc[4], myp[4];
        bool mykey[4];
        #pragma unroll
        for (int si=0; si<4; si++){
            int s = si*256 + tid;
            bool mid = (s != 0) && (s != SEQQ-1);
            myc[si] = -1; mykey[si] = false;
            if (mid){
                int cc = rel[b*(SEQQ-2) + s-1];
                myc[si] = cc;
                bool masked = (s >= 1+NUM_PM) && mask[b*NUM_VM + (s-1-NUM_PM)];
                if (!masked){ mykey[si] = true; myp[si] = atomicAdd(&cntS[cc], 1); }
            }
        }
        __syncthreads();
        {
            int v = cntS[tid];
            int incl = v;
            #pragma unroll
            for (int d=1; d<64; d<<=1){
                int n = __shfl_up(incl, d);
                if ((tid & 63) >= d) incl += n;
            }
            offS[tid] = incl - v;
            if ((tid & 63) == 63) wsum4[tid>>6] = incl;
        }
        __syncthreads();
        {
            int w = tid >> 6, base = 0;
            #pragma unroll
            for (int i=0;i<4;i++) if (i < w) base += wsum4[i];
            offS[tid] += base;
        }
        __syncthreads();
        #pragma unroll
        for (int si=0; si<4; si++){
            if (mykey[si]){
                int s = si*256 + tid;
                int pos = offS[myc[si]] + myp[si];
                memS[pos] = s;
                kmem[b*SEQQ + pos] = s;
            }
        }
        kcnt[b*256 + tid] = cntS[tid];
        koff[b*256 + tid] = offS[tid];
        __syncthreads();     // memS visible to all
        // per-query padded member rows
        #pragma unroll
        for (int si=0; si<4; si++){
            int s = si*256 + tid;
            if (myc[si] >= 0){
                int c = myc[si];
                int cnt = cntS[c], off = offS[c];
                pcnt[b*SEQQ + s] = cnt;
                poff[b*SEQQ + s] = b*SEQQ + off;
                int mrow[16];
                #pragma unroll
                for (int j=0;j<16;j++)
                    mrow[j] = (j < cnt) ? memS[off + j] : s;   // pad with self (safe addr)
                int4* prow = (int4*)&pmem[(size_t)(b*SEQQ + s)*16];
                prow[0] = (int4){mrow[0], mrow[1], mrow[2], mrow[3]};
                prow[1] = (int4){mrow[4], mrow[5], mrow[6], mrow[7]};
                prow[2] = (int4){mrow[8], mrow[9], mrow[10],mrow[11]};
                prow[3] = (int4){mrow[12],mrow[13],mrow[14],mrow[15]};
            }
        }
        // zero the 769 outputs of this batch (head uses atomicAdd)
        #pragma unroll
        for (int si=0; si<4; si++){
            int idx = si*256 + tid;
            if (idx < 769) outz[b*769 + idx] = 0.f;
        }
    } else {
        // ---- embed + LN1(layer0): wave per row
        int row = (bid - 2312)*4 + (tid>>6);
        int lane = tid & 63;
        int b = row >> 10, s = row & 1023;
        int col = lane*4;
        float4 out;
        if (s == 0){
            float v = num_step[b]; out = (float4){v,v,v,v};
        } else if (s == SEQQ-1){
            out = (float4){-1.f,-1.f,-1.f,-1.f};
        } else {
            const float* in; const float* W; const float* bias;
            if (s <= NUM_PM){ in = pm_states + (size_t)(b*NUM_PM + s-1)*16; W = pm_W; bias = pm_b; }
            else            { in = vm_states + (size_t)(b*NUM_VM + (s-1-NUM_PM))*16; W = vm_W; bias = vm_b; }
            float4 i0 = *(const float4*)in,      i1 = *(const float4*)(in+4);
            float4 i2 = *(const float4*)(in+8),  i3 = *(const float4*)(in+12);
            float in16[16] = {i0.x,i0.y,i0.z,i0.w, i1.x,i1.y,i1.z,i1.w,
                              i2.x,i2.y,i2.z,i2.w, i3.x,i3.y,i3.z,i3.w};
            out = *(const float4*)&bias[col];
            #pragma unroll
            for (int k=0;k<16;k++){
                float4 w4 = *(const float4*)&W[k*DD + col];
                out.x = fmaf(in16[k], w4.x, out.x);
                out.y = fmaf(in16[k], w4.y, out.y);
                out.z = fmaf(in16[k], w4.z, out.z);
                out.w = fmaf(in16[k], w4.w, out.w);
            }
        }
        *(float4*)&x[(size_t)row*DD + col] = out;
        float s1 = out.x+out.y+out.z+out.w;
        float s2 = fmaf(out.x,out.x, fmaf(out.y,out.y, fmaf(out.z,out.z, out.w*out.w)));
        #pragma unroll
        for (int off=1; off<64; off<<=1){ s1 += __shfl_xor(s1,off); s2 += __shfl_xor(s2,off); }
        float m    = s1*(1.0f/DD);
        float var  = s2*(1.0f/DD) - m*m;
        float rstd = rsqrtf(var + 1e-5f);
        float4 g4 = *(const float4*)&g[col];
        float4 b4 = *(const float4*)&beta[col];
        short4 o;
        o.x = (short)f2bf((out.x-m)*rstd*g4.x + b4.x);
        o.y = (short)f2bf((out.y-m)*rstd*g4.y + b4.y);
        o.z = (short)f2bf((out.z-m)*rstd*g4.z + b4.z);
        o.w = (short)f2bf((out.w-m)*rstd*g4.w + b4.w);
        *(short4*)&h[(size_t)row*DD + col] = o;
    }
}

// ---------------------------------------------------------------- layernorm: wave per row, f32 in -> bf16 out
__global__ void ln_kernel(const float* __restrict__ x, const float* __restrict__ g,
                          const float* __restrict__ bta, u16* __restrict__ out)
{
    int row = blockIdx.x*4 + (threadIdx.x>>6);
    int lane = threadIdx.x & 63;
    const float4 v = *(const float4*)&x[(size_t)row*DD + lane*4];
    float s1 = v.x+v.y+v.z+v.w;
    float s2 = fmaf(v.x,v.x, fmaf(v.y,v.y, fmaf(v.z,v.z, v.w*v.w)));
    #pragma unroll
    for (int off=1; off<64; off<<=1){ s1 += __shfl_xor(s1,off); s2 += __shfl_xor(s2,off); }
    float m    = s1*(1.0f/DD);
    float var  = s2*(1.0f/DD) - m*m;
    float rstd = rsqrtf(var + 1e-5f);
    float4 g4 = *(const float4*)&g[lane*4];
    float4 b4 = *(const float4*)&bta[lane*4];
    short4 o;
    o.x = (short)f2bf((v.x-m)*rstd*g4.x + b4.x);
    o.y = (short)f2bf((v.y-m)*rstd*g4.y + b4.y);
    o.z = (short)f2bf((v.z-m)*rstd*g4.z + b4.z);
    o.w = (short)f2bf((v.w-m)*rstd*g4.w + b4.w);
    *(short4*)&out[(size_t)row*DD + lane*4] = o;
}

// ---------------------------------------------------------------- MFMA GEMM 64x128, dbuf: C bf16 = A@Bt^T + bias   (QKV)
__launch_bounds__(256)
__global__ void qgemm_kernel(const u16* __restrict__ A, const u16* __restrict__ Bt,
                             const float* __restrict__ bias, u16* __restrict__ C,
                             int N, int K)
{
    __shared__ u16 As[2][64][32];
    __shared__ u16 Bs[2][128][32];
    int tid = threadIdx.x;
    int wid = tid >> 6, lane = tid & 63;
    int wr = wid >> 1, wc = wid & 1;            // wave tile 32x64
    int row0 = blockIdx.y*64, col0 = blockIdx.x*128;
    int l15 = lane & 15, lh = lane >> 4;

    const u16* Ag = A  + (size_t)(row0 + wid*16 + (lane>>2))*K + (lane&3)*8;
    const u16* Bg = Bt + (size_t)(col0 + wid*32 + (lane>>2))*K + (lane&3)*8;

#define STAGE_Q(buf, k0) do{ \
    GLOAD16(Ag + (k0),          &As[buf][wid*16][0]);    \
    GLOAD16(Bg + (k0),          &Bs[buf][wid*32][0]);    \
    GLOAD16(Bg + (k0) + 16*K,   &Bs[buf][wid*32+16][0]); }while(0)

    f32x4 acc[2][4] = {};
    int nk = K >> 5;
    STAGE_Q(0, 0);
    __syncthreads();
    for (int kt = 0; kt < nk; kt++){
        int cur = kt & 1;
        if (kt+1 < nk) STAGE_Q(cur^1, (kt+1)*32);
        bf16x8 af[2], bfv[4];
        #pragma unroll
        for (int i=0;i<2;i++)
            af[i] = *(const bf16x8*)&As[cur][wr*32 + i*16 + l15][lh*8];
        #pragma unroll
        for (int j=0;j<4;j++)
            bfv[j] = *(const bf16x8*)&Bs[cur][wc*64 + j*16 + l15][lh*8];
        #pragma unroll
        for (int i=0;i<2;i++)
            #pragma unroll
            for (int j=0;j<4;j++)
                acc[i][j] = __builtin_amdgcn_mfma_f32_16x16x32_bf16(af[i], bfv[j], acc[i][j], 0,0,0);
        __syncthreads();
    }
#undef STAGE_Q

    #pragma unroll
    for (int i=0;i<2;i++){
        #pragma unroll
        for (int j=0;j<4;j++){
            int col = col0 + wc*64 + j*16 + l15;
            float bb = bias[col];
            #pragma unroll
            for (int r=0;r<4;r++){
                int row = row0 + wr*32 + i*16 + lh*4 + r;
                C[(size_t)row*N + col] = f2bf(acc[i][j][r] + bb);
            }
        }
    }
}

// ---------------------------------------------------------------- MFMA GEMM 128x128, dbuf: C bf16 = gelu(A@Bt^T + bias)   (FF1)
__launch_bounds__(256)
__global__ void mgemm_kernel(const u16* __restrict__ A, const u16* __restrict__ Bt,
                             const float* __restrict__ bias, u16* __restrict__ C,
                             int N, int K)
{
    __shared__ u16 As[2][128][32];
    __shared__ u16 Bs[2][128][32];
    int tid = threadIdx.x;
    int wid = tid >> 6, lane = tid & 63;
    int wr = wid >> 1, wc = wid & 1;
    int row0 = blockIdx.y*128, col0 = blockIdx.x*128;
    int l15 = lane & 15, lh = lane >> 4;

    const u16* Ag = A  + (size_t)(row0 + wid*32 + (lane>>2))*K + (lane&3)*8;
    const u16* Bg = Bt + (size_t)(col0 + wid*32 + (lane>>2))*K + (lane&3)*8;

#define STAGE_M(buf, k0) do{ \
    GLOAD16(Ag + (k0),          &As[buf][wid*32][0]);    \
    GLOAD16(Ag + (k0) + 16*K,   &As[buf][wid*32+16][0]); \
    GLOAD16(Bg + (k0),          &Bs[buf][wid*32][0]);    \
    GLOAD16(Bg + (k0) + 16*K,   &Bs[buf][wid*32+16][0]); }while(0)

    f32x4 acc[4][4] = {};
    int nk = K >> 5;
    STAGE_M(0, 0);
    __syncthreads();
    for (int kt = 0; kt < nk; kt++){
        int cur = kt & 1;
        if (kt+1 < nk) STAGE_M(cur^1, (kt+1)*32);
        bf16x8 af[4], bfv[4];
        #pragma unroll
        for (int f=0; f<4; f++){
            af[f]  = *(const bf16x8*)&As[cur][wr*64 + f*16 + l15][lh*8];
            bfv[f] = *(const bf16x8*)&Bs[cur][wc*64 + f*16 + l15][lh*8];
        }
        #pragma unroll
        for (int i=0;i<4;i++)
            #pragma unroll
            for (int j=0;j<4;j++)
                acc[i][j] = __builtin_amdgcn_mfma_f32_16x16x32_bf16(af[i], bfv[j], acc[i][j], 0,0,0);
        __syncthreads();
    }
#undef STAGE_M

    #pragma unroll
    for (int i=0;i<4;i++){
        #pragma unroll
        for (int j=0;j<4;j++){
            int col = col0 + wc*64 + j*16 + l15;
            float bb = bias[col];
            #pragma unroll
            for (int r=0;r<4;r++){
                int row = row0 + wr*64 + i*16 + lh*4 + r;
                C[(size_t)row*N + col] = f2bf(gelu_tanh(acc[i][j][r] + bb));
            }
        }
    }
}

// ---------------------------------------------------------------- MFMA GEMM 64x64, dbuf: x[M,256] += A@Bt^T + bias  (+head)
template<int HEAD>
__launch_bounds__(256)
__global__ void mgemm64_kernel(const u16* __restrict__ A, const u16* __restrict__ Bt,
                               const float* __restrict__ bias, float* __restrict__ x,
                               const float* __restrict__ out_W, const float* __restrict__ out_b,
                               const float* __restrict__ crit_W, const float* __restrict__ crit_b,
                               float* __restrict__ out, int K)
{
    __shared__ u16 As[2][64][32];
    __shared__ u16 Bs[2][64][32];
    int tid = threadIdx.x;
    int wid = tid >> 6, lane = tid & 63;
    int wr = wid >> 1, wc = wid & 1;            // wave tile 32x32
    int row0 = blockIdx.y*64, col0 = blockIdx.x*64;
    int l15 = lane & 15, lh = lane >> 4;

    const u16* Ag = A  + (size_t)(row0 + wid*16 + (lane>>2))*K + (lane&3)*8;
    const u16* Bg = Bt + (size_t)(col0 + wid*16 + (lane>>2))*K + (lane&3)*8;

#define STAGE_S(buf, k0) do{ \
    GLOAD16(Ag + (k0), &As[buf][wid*16][0]); \
    GLOAD16(Bg + (k0), &Bs[buf][wid*16][0]); }while(0)

    f32x4 acc[2][2] = {};
    int nk = K >> 5;
    STAGE_S(0, 0);
    __syncthreads();
    for (int kt = 0; kt < nk; kt++){
        int cur = kt & 1;
        if (kt+1 < nk) STAGE_S(cur^1, (kt+1)*32);
        bf16x8 af[2], bfv[2];
        #pragma unroll
        for (int i=0;i<2;i++)
            af[i] = *(const bf16x8*)&As[cur][wr*32 + i*16 + l15][lh*8];
        #pragma unroll
        for (int j=0;j<2;j++)
            bfv[j] = *(const bf16x8*)&Bs[cur][wc*32 + j*16 + l15][lh*8];
        #pragma unroll
        for (int i=0;i<2;i++)
            #pragma unroll
            for (int j=0;j<2;j++)
                acc[i][j] = __builtin_amdgcn_mfma_f32_16x16x32_bf16(af[i], bfv[j], acc[i][j], 0,0,0);
        __syncthreads();
    }
#undef STAGE_S

    #pragma unroll
    for (int i=0;i<2;i++){
        #pragma unroll
        for (int r=0;r<4;r++){
            int row = row0 + wr*32 + i*16 + lh*4 + r;
            float hp = 0.f;
            int s = row & 1023;
            #pragma unroll
            for (int j=0;j<2;j++){
                int col = col0 + wc*32 + j*16 + l15;
                size_t idx = (size_t)row*DD + col;
                float v = acc[i][j][r] + bias[col] + x[idx];
                x[idx] = v;
                if (HEAD){
                    float w = (s == 1023) ? crit_W[col] : out_W[col];
                    hp = fmaf(v, w, hp);
                }
            }
            if (HEAD && s >= 1 + NUM_PM){
                hp += __shfl_xor(hp, 1);
                hp += __shfl_xor(hp, 2);
                hp += __shfl_xor(hp, 4);
                hp += __shfl_xor(hp, 8);
                if (l15 == 0){
                    int b = row >> 10;
                    int jj = (s == 1023) ? 768 : (s - (1 + NUM_PM));
                    float add = hp;
                    if (blockIdx.x == 0 && wc == 0)
                        add += (s == 1023) ? crit_b[0] : out_b[0];
                    atomicAdd(&out[b*769 + jj], add);
                }
            }
        }
    }
}

// ---------------------------------------------------------------- attention: wave per query, precomputed padded member rows
// lane = h*8+i holds dims [lane*4, lane*4+4); 2 dependent L2 trips per query
__launch_bounds__(256)
__global__ void attn_kernel(const u16* __restrict__ qkv,
                            const int* __restrict__ pcnt, const int* __restrict__ pmem,
                            const int* __restrict__ poff, const int* __restrict__ kmem,
                            u16* __restrict__ o)
{
    int gq = blockIdx.x*4 + (threadIdx.x >> 6);
    int lane = threadIdx.x & 63;
    int b = gq >> 10, s = gq & 1023;
    const float scale = 0.17677669529663687f;       // 1/sqrt(32)

    if (s == 0 || s == SEQQ-1){
        // single unmasked self-key -> softmax == 1 -> o = V[s]
        const u16* vrow = qkv + (size_t)gq*768 + 512 + lane*4;
        *(short4*)(o + (size_t)gq*DD + lane*4) = *(const short4*)vrow;
        return;
    }

    const u16* qb = qkv + (size_t)gq*768 + lane*4;
    short4 q4i = *(const short4*)qb;
    float qx = bf2f((u16)q4i.x)*scale, qy = bf2f((u16)q4i.y)*scale,
          qz = bf2f((u16)q4i.z)*scale, qw = bf2f((u16)q4i.w)*scale;

    int cnt = pcnt[gq];
    const int4* prow = (const int4*)&pmem[(size_t)gq*16];
    int4 m0 = prow[0], m1 = prow[1], m2 = prow[2], m3 = prow[3];

    float m_run = -1e30f, l_run = 0.f;
    float ax=0.f, ay=0.f, az=0.f, aw=0.f;

#define ACHUNK(BASE, MV) do{                                              \
    if ((BASE) < cnt){                                                    \
        short4 k4[4], v4[4];                                              \
        const int mi0=(MV).x, mi1=(MV).y, mi2=(MV).z, mi3=(MV).w;         \
        const u16* kb0 = qkv + (size_t)(b*SEQQ + mi0)*768 + 256 + lane*4; \
        const u16* kb1 = qkv + (size_t)(b*SEQQ + mi1)*768 + 256 + lane*4; \
        const u16* kb2 = qkv + (size_t)(b*SEQQ + mi2)*768 + 256 + lane*4; \
        const u16* kb3 = qkv + (size_t)(b*SEQQ + mi3)*768 + 256 + lane*4; \
        k4[0]=*(const short4*)kb0; v4[0]=*(const short4*)(kb0+256);       \
        k4[1]=*(const short4*)kb1; v4[1]=*(const short4*)(kb1+256);       \
        k4[2]=*(const short4*)kb2; v4[2]=*(const short4*)(kb2+256);       \
        k4[3]=*(const short4*)kb3; v4[3]=*(const short4*)(kb3+256);       \
        _Pragma("unroll")                                                 \
        for (int k=0;k<4;k++){                                            \
            if ((BASE) + k < cnt){                                        \
                float sc = qx*bf2f((u16)k4[k].x) + qy*bf2f((u16)k4[k].y)  \
                         + qz*bf2f((u16)k4[k].z) + qw*bf2f((u16)k4[k].w); \
                sc += __shfl_xor(sc, 1);                                  \
                sc += __shfl_xor(sc, 2);                                  \
                sc += __shfl_xor(sc, 4);                                  \
                float mn = fmaxf(m_run, sc);                              \
                float corr = __expf(m_run - mn);                          \
                float p = __expf(sc - mn);                                \
                l_run = l_run*corr + p;                                   \
                ax = ax*corr + p*bf2f((u16)v4[k].x);                      \
                ay = ay*corr + p*bf2f((u16)v4[k].y);                      \
                az = az*corr + p*bf2f((u16)v4[k].z);                      \
                aw = aw*corr + p*bf2f((u16)v4[k].w);                      \
                m_run = mn;                                               \
            }                                                             \
        }                                                                 \
    } }while(0)

    if (cnt <= 16){
        ACHUNK(0,  m0);
        ACHUNK(4,  m1);
        ACHUNK(8,  m2);
        ACHUNK(12, m3);
    } else {
        // extremely rare: full gather via kmem
        const int* klist = kmem + poff[gq];
        for (int j0 = 0; j0 < cnt; j0 += 4){
            short4 k4[4], v4[4];
            #pragma unroll
            for (int k=0;k<4;k++){
                int jj = j0 + k; jj = (jj < cnt) ? jj : (cnt-1);
                int mi = klist[jj];
                const u16* kb = qkv + (size_t)(b*SEQQ + mi)*768 + 256 + lane*4;
                k4[k] = *(const short4*)kb;
                v4[k] = *(const short4*)(kb + 256);
            }
            #pragma unroll
            for (int k=0;k<4;k++){
                if (j0 + k < cnt){
                    float sc = qx*bf2f((u16)k4[k].x) + qy*bf2f((u16)k4[k].y)
                             + qz*bf2f((u16)k4[k].z) + qw*bf2f((u16)k4[k].w);
                    sc += __shfl_xor(sc, 1);
                    sc += __shfl_xor(sc, 2);
                    sc += __shfl_xor(sc, 4);
                    float mn = fmaxf(m_run, sc);
                    float corr = __expf(m_run - mn);
                    float p = __expf(sc - mn);
                    l_run = l_run*corr + p;
                    ax = ax*corr + p*bf2f((u16)v4[k].x);
                    ay = ay*corr + p*bf2f((u16)v4[k].y);
                    az = az*corr + p*bf2f((u16)v4[k].z);
                    aw = aw*corr + p*bf2f((u16)v4[k].w);
                    m_run = mn;
                }
            }
        }
    }
#undef ACHUNK

    float inv = (l_run > 0.f) ? 1.0f/l_run : 0.f;
    u16* orow = o + (size_t)gq*DD + lane*4;
    short4 outv;
    outv.x = (short)f2bf(ax*inv); outv.y = (short)f2bf(ay*inv);
    outv.z = (short)f2bf(az*inv); outv.w = (short)f2bf(aw*inv);
    *(short4*)orow = outv;
}

// ---------------------------------------------------------------- launch
extern "C" void kernel_launch(void* const* d_in, const int* in_sizes, int n_in,
                              void* d_out, int out_size, void* d_ws, size_t ws_size,
                              hipStream_t stream)
{
    const float* vm_states = (const float*)d_in[0];
    const float* num_step  = (const float*)d_in[1];
    const float* pm_states = (const float*)d_in[2];
    const int*   rel       = (const int*)d_in[3];
    const unsigned char* mask = (const unsigned char*)d_in[4];
    const float* pm_W = (const float*)d_in[5];
    const float* pm_b = (const float*)d_in[6];
    const float* vm_W = (const float*)d_in[7];
    const float* vm_b = (const float*)d_in[8];
    const float* Wqkv = (const float*)d_in[9];
    const float* bqkv = (const float*)d_in[10];
    const float* Wo   = (const float*)d_in[11];
    const float* bo   = (const float*)d_in[12];
    const float* ln1g = (const float*)d_in[13];
    const float* ln1b = (const float*)d_in[14];
    const float* ln2g = (const float*)d_in[15];
    const float* ln2b = (const float*)d_in[16];
    const float* W1   = (const float*)d_in[17];
    const float* b1   = (const float*)d_in[18];
    const float* W2   = (const float*)d_in[19];
    const float* b2   = (const float*)d_in[20];
    const float* out_W = (const float*)d_in[21];
    const float* out_b = (const float*)d_in[22];
    const float* crit_W = (const float*)d_in[23];
    const float* crit_b = (const float*)d_in[24];

    char* ws = (char*)d_ws;
    const size_t MB = 1024*1024;
    float* x    = (float*)(ws);                      // [8192][256] f32   :  0..8 MB
    u16*   hbuf = (u16*)(ws + 8*MB);                 // [8192][256] bf16  :  8..12
    u16*   aout = (u16*)(ws + 12*MB);                // [8192][256] bf16  : 12..16
    u16*   qkv  = (u16*)(ws + 16*MB);                // [8192][768] bf16  : 16..28
    u16*   ff1  = (u16*)(ws + 28*MB);                // [8192][1024] bf16 : 28..44
    u16*   wq   = (u16*)(ws + 44*MB);                // [3][768][256]
    u16*   wo   = wq + (size_t)3*768*256;            // [3][256][256]
    u16*   w1   = wo + (size_t)3*256*256;            // [3][1024][256]
    u16*   w2   = w1 + (size_t)3*1024*256;           // [3][256][1024]
    int*   kcnt = (int*)(ws + 50*MB);                // [8][256]
    int*   koff = kcnt + NB*256;                     // [8][256]
    int*   kmem = koff + NB*256;                     // [8][1024]
    int*   pcnt = kmem + NB*SEQQ;                    // [8192]
    int*   poff = pcnt + MROWS;                      // [8192]
    int*   pmem = poff + MROWS;                      // [8192][16]

    prologue_kernel<<<4360, 256, 0, stream>>>(Wqkv, Wo, W1, W2, wq, wo, w1, w2,
                                              rel, mask, kcnt, koff, kmem, pcnt, poff, pmem,
                                              vm_states, num_step, pm_states,
                                              pm_W, pm_b, vm_W, vm_b,
                                              ln1g, ln1b, x, hbuf, (float*)d_out);
    for (int i=0;i<3;i++){
        qgemm_kernel<<<dim3(768/128, MROWS/64),256,0,stream>>>(
            hbuf, wq + (size_t)i*768*256, bqkv + i*768, qkv, 768, 256);
        attn_kernel<<<MROWS/4, 256, 0, stream>>>(qkv, pcnt, pmem, poff, kmem, aout);
        mgemm64_kernel<0><<<dim3(256/64, MROWS/64),256,0,stream>>>(
            aout, wo + (size_t)i*256*256, bo + i*DD, x,
            nullptr, nullptr, nullptr, nullptr, nullptr, 256);
        ln_kernel<<<MROWS/4,256,0,stream>>>(x, ln2g + i*DD, ln2b + i*DD, hbuf);
        mgemm_kernel<<<dim3(1024/128, MROWS/128),256,0,stream>>>(
            hbuf, w1 + (size_t)i*1024*256, b1 + i*FF, ff1, 1024, 256);
        if (i < 2){
            mgemm64_kernel<0><<<dim3(256/64, MROWS/64),256,0,stream>>>(
                ff1, w2 + (size_t)i*256*1024, b2 + i*DD, x,
                nullptr, nullptr, nullptr, nullptr, nullptr, 1024);
            ln_kernel<<<MROWS/4,256,0,stream>>>(x, ln1g + (i+1)*DD, ln1b + (i+1)*DD, hbuf);
        } else {
            mgemm64_kernel<1><<<dim3(256/64, MROWS/64),256,0,stream>>>(
                ff1, w2 + (size_t)i*256*1024, b2 + i*DD, x,
                out_W, out_b, crit_W, crit_b, (float*)d_out, 1024);
        }
    }
}

// Round 11
// 324.889 us; speedup vs baseline: 1.3895x; 1.0230x over previous
//
#include <hip/hip_runtime.h>
#include <hip/hip_bf16.h>
#include <math.h>

#define NUM_PM 254
#define NUM_VM 768
#define SEQQ   1024      // NUM_PM + NUM_VM + 2
#define NH     8
#define DD     256
#define DH     32
#define FF     1024
#define NB     8
#define MROWS  (NB*SEQQ) // 8192

typedef unsigned short u16;
typedef __attribute__((ext_vector_type(8))) short bf16x8;
typedef __attribute__((ext_vector_type(4))) float f32x4;

__device__ __forceinline__ float bf2f(u16 u){
    union { float f; unsigned int i; } c; c.i = ((unsigned int)u) << 16; return c.f;
}
__device__ __forceinline__ u16 f2bf(float f){
    union { float f; unsigned int u; } c; c.f = f;
    unsigned int r = c.u + 0x7FFFu + ((c.u >> 16) & 1u);   // RNE
    return (u16)(r >> 16);
}
__device__ __forceinline__ float gelu_tanh(float x){
    float x3 = x*x*x;
    float t = tanhf(0.7978845608028654f*(x + 0.044715f*x3));
    return 0.5f*x*(1.0f+t);
}

#define GLOAD16(gp, lp) __builtin_amdgcn_global_load_lds( \
    (const __attribute__((address_space(1))) void*)(gp), \
    (__attribute__((address_space(3))) void*)(lp), 16, 0, 0)

// ---------------------------------------------------------------- prologue:
// tcast (0..2303) | group build + pq tables + out-zero (2304..2311) | embed+LN1 (2312..4359)
__global__ void prologue_kernel(const float* __restrict__ Wqkv, const float* __restrict__ Wo,
                                const float* __restrict__ W1,   const float* __restrict__ W2,
                                u16* __restrict__ wq, u16* __restrict__ wo,
                                u16* __restrict__ w1, u16* __restrict__ w2,
                                const int* __restrict__ rel, const unsigned char* __restrict__ mask,
                                int* __restrict__ kcnt, int* __restrict__ koff, int* __restrict__ kmem,
                                int* __restrict__ pcnt, int* __restrict__ poff, int* __restrict__ pmem,
                                const float* __restrict__ vm_states,
                                const float* __restrict__ num_step,
                                const float* __restrict__ pm_states,
                                const float* __restrict__ pm_W, const float* __restrict__ pm_b,
                                const float* __restrict__ vm_W, const float* __restrict__ vm_b,
                                const float* __restrict__ g, const float* __restrict__ beta,
                                float* __restrict__ x, u16* __restrict__ h,
                                float* __restrict__ outz)
{
    __shared__ float t[32][33];
    __shared__ int cntS[256], offS[256], wsum4[4];
    __shared__ int memS[1040];
    int bid = blockIdx.x;
    int tid = threadIdx.x;
    if (bid < 2304){
        // ---- transpose-cast one 32x32 tile
        int id = bid;
        const float* in; u16* out; int K, N, layer, tile;
        if (id < 576)       { in=Wqkv; out=wq; K=256;  N=768;  layer=id/192; tile=id%192; }
        else if (id < 768)  { id-=576;  in=Wo; out=wo; K=256;  N=256;  layer=id/64;  tile=id%64;  }
        else if (id < 1536) { id-=768;  in=W1; out=w1; K=256;  N=1024; layer=id/256; tile=id%256; }
        else                { id-=1536; in=W2; out=w2; K=1024; N=256;  layer=id/256; tile=id%256; }
        int ntx = N/32;
        int n0 = (tile % ntx)*32, k0 = (tile / ntx)*32;
        size_t lofs = (size_t)layer * K * N;
        int tx = tid & 31, ty = tid >> 5;
        #pragma unroll
        for (int i=0;i<4;i++)
            t[ty + i*8][tx] = in[lofs + (size_t)(k0 + ty + i*8)*N + n0 + tx];
        __syncthreads();
        #pragma unroll
        for (int i=0;i<4;i++)
            out[lofs + (size_t)(n0 + ty + i*8)*K + k0 + tx] = f2bf(t[tx][ty + i*8]);
    } else if (bid < 2312){
        // ---- group build for batch b (counting sort of valid keys by code) + pq tables
        int b = bid - 2304;
        cntS[tid] = 0;
        __syncthreads();
        int myc[4], myp[4];
        bool mykey[4];
        #pragma unroll
        for (int si=0; si<4; si++){
            int s = si*256 + tid;
            bool mid = (s != 0) && (s != SEQQ-1);
            myc[si] = -1; mykey[si] = false;
            if (mid){
                int cc = rel[b*(SEQQ-2) + s-1];
                myc[si] = cc;
                bool masked = (s >= 1+NUM_PM) && mask[b*NUM_VM + (s-1-NUM_PM)];
                if (!masked){ mykey[si] = true; myp[si] = atomicAdd(&cntS[cc], 1); }
            }
        }
        __syncthreads();
        {
            int v = cntS[tid];
            int incl = v;
            #pragma unroll
            for (int d=1; d<64; d<<=1){
                int n = __shfl_up(incl, d);
                if ((tid & 63) >= d) incl += n;
            }
            offS[tid] = incl - v;
            if ((tid & 63) == 63) wsum4[tid>>6] = incl;
        }
        __syncthreads();
        {
            int w = tid >> 6, base = 0;
            #pragma unroll
            for (int i=0;i<4;i++) if (i < w) base += wsum4[i];
            offS[tid] += base;
        }
        __syncthreads();
        #pragma unroll
        for (int si=0; si<4; si++){
            if (mykey[si]){
                int s = si*256 + tid;
                int pos = offS[myc[si]] + myp[si];
                memS[pos] = s;
                kmem[b*SEQQ + pos] = s;
            }
        }
        kcnt[b*256 + tid] = cntS[tid];
        koff[b*256 + tid] = offS[tid];
        __syncthreads();     // memS visible to all
        // per-query padded member rows
        #pragma unroll
        for (int si=0; si<4; si++){
            int s = si*256 + tid;
            if (myc[si] >= 0){
                int c = myc[si];
                int cnt = cntS[c], off = offS[c];
                pcnt[b*SEQQ + s] = cnt;
                poff[b*SEQQ + s] = b*SEQQ + off;
                int mrow[16];
                #pragma unroll
                for (int j=0;j<16;j++)
                    mrow[j] = (j < cnt) ? memS[off + j] : s;   // pad with self (safe addr)
                int4* prow = (int4*)&pmem[(size_t)(b*SEQQ + s)*16];
                prow[0] = (int4){mrow[0], mrow[1], mrow[2], mrow[3]};
                prow[1] = (int4){mrow[4], mrow[5], mrow[6], mrow[7]};
                prow[2] = (int4){mrow[8], mrow[9], mrow[10],mrow[11]};
                prow[3] = (int4){mrow[12],mrow[13],mrow[14],mrow[15]};
            }
        }
        // zero the 769 outputs of this batch (head uses atomicAdd)
        #pragma unroll
        for (int si=0; si<4; si++){
            int idx = si*256 + tid;
            if (idx < 769) outz[b*769 + idx] = 0.f;
        }
    } else {
        // ---- embed + LN1(layer0): wave per row
        int row = (bid - 2312)*4 + (tid>>6);
        int lane = tid & 63;
        int b = row >> 10, s = row & 1023;
        int col = lane*4;
        float4 out;
        if (s == 0){
            float v = num_step[b]; out = (float4){v,v,v,v};
        } else if (s == SEQQ-1){
            out = (float4){-1.f,-1.f,-1.f,-1.f};
        } else {
            const float* in; const float* W; const float* bias;
            if (s <= NUM_PM){ in = pm_states + (size_t)(b*NUM_PM + s-1)*16; W = pm_W; bias = pm_b; }
            else            { in = vm_states + (size_t)(b*NUM_VM + (s-1-NUM_PM))*16; W = vm_W; bias = vm_b; }
            float4 i0 = *(const float4*)in,      i1 = *(const float4*)(in+4);
            float4 i2 = *(const float4*)(in+8),  i3 = *(const float4*)(in+12);
            float in16[16] = {i0.x,i0.y,i0.z,i0.w, i1.x,i1.y,i1.z,i1.w,
                              i2.x,i2.y,i2.z,i2.w, i3.x,i3.y,i3.z,i3.w};
            out = *(const float4*)&bias[col];
            #pragma unroll
            for (int k=0;k<16;k++){
                float4 w4 = *(const float4*)&W[k*DD + col];
                out.x = fmaf(in16[k], w4.x, out.x);
                out.y = fmaf(in16[k], w4.y, out.y);
                out.z = fmaf(in16[k], w4.z, out.z);
                out.w = fmaf(in16[k], w4.w, out.w);
            }
        }
        *(float4*)&x[(size_t)row*DD + col] = out;
        float s1 = out.x+out.y+out.z+out.w;
        float s2 = fmaf(out.x,out.x, fmaf(out.y,out.y, fmaf(out.z,out.z, out.w*out.w)));
        #pragma unroll
        for (int off=1; off<64; off<<=1){ s1 += __shfl_xor(s1,off); s2 += __shfl_xor(s2,off); }
        float m    = s1*(1.0f/DD);
        float var  = s2*(1.0f/DD) - m*m;
        float rstd = rsqrtf(var + 1e-5f);
        float4 g4 = *(const float4*)&g[col];
        float4 b4 = *(const float4*)&beta[col];
        short4 o;
        o.x = (short)f2bf((out.x-m)*rstd*g4.x + b4.x);
        o.y = (short)f2bf((out.y-m)*rstd*g4.y + b4.y);
        o.z = (short)f2bf((out.z-m)*rstd*g4.z + b4.z);
        o.w = (short)f2bf((out.w-m)*rstd*g4.w + b4.w);
        *(short4*)&h[(size_t)row*DD + col] = o;
    }
}

// ---------------------------------------------------------------- layernorm: wave per row, f32 in -> bf16 out
__global__ void ln_kernel(const float* __restrict__ x, const float* __restrict__ g,
                          const float* __restrict__ bta, u16* __restrict__ out)
{
    int row = blockIdx.x*4 + (threadIdx.x>>6);
    int lane = threadIdx.x & 63;
    const float4 v = *(const float4*)&x[(size_t)row*DD + lane*4];
    float s1 = v.x+v.y+v.z+v.w;
    float s2 = fmaf(v.x,v.x, fmaf(v.y,v.y, fmaf(v.z,v.z, v.w*v.w)));
    #pragma unroll
    for (int off=1; off<64; off<<=1){ s1 += __shfl_xor(s1,off); s2 += __shfl_xor(s2,off); }
    float m    = s1*(1.0f/DD);
    float var  = s2*(1.0f/DD) - m*m;
    float rstd = rsqrtf(var + 1e-5f);
    float4 g4 = *(const float4*)&g[lane*4];
    float4 b4 = *(const float4*)&bta[lane*4];
    short4 o;
    o.x = (short)f2bf((v.x-m)*rstd*g4.x + b4.x);
    o.y = (short)f2bf((v.y-m)*rstd*g4.y + b4.y);
    o.z = (short)f2bf((v.z-m)*rstd*g4.z + b4.z);
    o.w = (short)f2bf((v.w-m)*rstd*g4.w + b4.w);
    *(short4*)&out[(size_t)row*DD + lane*4] = o;
}

// T4 counted-vmcnt waits: keep prefetched tiles in flight across the barrier.
#define VMWAIT(N) asm volatile("s_waitcnt vmcnt(" #N ")" ::: "memory")

// ---------------------------------------------------------------- MFMA GEMM 64x128, 3-buf counted-vmcnt: C bf16 = A@Bt^T + bias (QKV)
__launch_bounds__(256)
__global__ void qgemm_kernel(const u16* __restrict__ A, const u16* __restrict__ Bt,
                             const float* __restrict__ bias, u16* __restrict__ C,
                             int N, int K)
{
    __shared__ u16 As[3][64][32];
    __shared__ u16 Bs[3][128][32];
    int tid = threadIdx.x;
    int wid = tid >> 6, lane = tid & 63;
    int wr = wid >> 1, wc = wid & 1;            // wave tile 32x64
    int row0 = blockIdx.y*64, col0 = blockIdx.x*128;
    int l15 = lane & 15, lh = lane >> 4;

    const u16* Ag = A  + (size_t)(row0 + wid*16 + (lane>>2))*K + (lane&3)*8;
    const u16* Bg = Bt + (size_t)(col0 + wid*32 + (lane>>2))*K + (lane&3)*8;

#define STAGE_Q(buf, k0) do{ \
    GLOAD16(Ag + (k0),          &As[buf][wid*16][0]);    \
    GLOAD16(Bg + (k0),          &Bs[buf][wid*32][0]);    \
    GLOAD16(Bg + (k0) + 16*K,   &Bs[buf][wid*32+16][0]); }while(0)

    f32x4 acc[2][4] = {};
    int nk = K >> 5;
    STAGE_Q(0, 0);
    STAGE_Q(1, 32);
    for (int kt = 0; kt < nk; kt++){
        int cur = kt % 3;
        if (kt+1 < nk) VMWAIT(3);   // oldest tile done; next tile's 3 loads stay in flight
        else           VMWAIT(0);
        __builtin_amdgcn_s_barrier();
        bf16x8 af[2], bfv[4];
        #pragma unroll
        for (int i=0;i<2;i++)
            af[i] = *(const bf16x8*)&As[cur][wr*32 + i*16 + l15][lh*8];
        #pragma unroll
        for (int j=0;j<4;j++)
            bfv[j] = *(const bf16x8*)&Bs[cur][wc*64 + j*16 + l15][lh*8];
        if (kt+2 < nk) STAGE_Q((kt+2)%3, (kt+2)*32);
        #pragma unroll
        for (int i=0;i<2;i++)
            #pragma unroll
            for (int j=0;j<4;j++)
                acc[i][j] = __builtin_amdgcn_mfma_f32_16x16x32_bf16(af[i], bfv[j], acc[i][j], 0,0,0);
    }
#undef STAGE_Q

    #pragma unroll
    for (int i=0;i<2;i++){
        #pragma unroll
        for (int j=0;j<4;j++){
            int col = col0 + wc*64 + j*16 + l15;
            float bb = bias[col];
            #pragma unroll
            for (int r=0;r<4;r++){
                int row = row0 + wr*32 + i*16 + lh*4 + r;
                C[(size_t)row*N + col] = f2bf(acc[i][j][r] + bb);
            }
        }
    }
}

// ---------------------------------------------------------------- MFMA GEMM 128x128, 3-buf counted-vmcnt: C bf16 = gelu(A@Bt^T + bias) (FF1)
__launch_bounds__(256)
__global__ void mgemm_kernel(const u16* __restrict__ A, const u16* __restrict__ Bt,
                             const float* __restrict__ bias, u16* __restrict__ C,
                             int N, int K)
{
    __shared__ u16 As[3][128][32];
    __shared__ u16 Bs[3][128][32];
    int tid = threadIdx.x;
    int wid = tid >> 6, lane = tid & 63;
    int wr = wid >> 1, wc = wid & 1;
    int row0 = blockIdx.y*128, col0 = blockIdx.x*128;
    int l15 = lane & 15, lh = lane >> 4;

    const u16* Ag = A  + (size_t)(row0 + wid*32 + (lane>>2))*K + (lane&3)*8;
    const u16* Bg = Bt + (size_t)(col0 + wid*32 + (lane>>2))*K + (lane&3)*8;

#define STAGE_M(buf, k0) do{ \
    GLOAD16(Ag + (k0),          &As[buf][wid*32][0]);    \
    GLOAD16(Ag + (k0) + 16*K,   &As[buf][wid*32+16][0]); \
    GLOAD16(Bg + (k0),          &Bs[buf][wid*32][0]);    \
    GLOAD16(Bg + (k0) + 16*K,   &Bs[buf][wid*32+16][0]); }while(0)

    f32x4 acc[4][4] = {};
    int nk = K >> 5;
    STAGE_M(0, 0);
    STAGE_M(1, 32);
    for (int kt = 0; kt < nk; kt++){
        int cur = kt % 3;
        if (kt+1 < nk) VMWAIT(4);
        else           VMWAIT(0);
        __builtin_amdgcn_s_barrier();
        bf16x8 af[4], bfv[4];
        #pragma unroll
        for (int f=0; f<4; f++){
            af[f]  = *(const bf16x8*)&As[cur][wr*64 + f*16 + l15][lh*8];
            bfv[f] = *(const bf16x8*)&Bs[cur][wc*64 + f*16 + l15][lh*8];
        }
        if (kt+2 < nk) STAGE_M((kt+2)%3, (kt+2)*32);
        #pragma unroll
        for (int i=0;i<4;i++)
            #pragma unroll
            for (int j=0;j<4;j++)
                acc[i][j] = __builtin_amdgcn_mfma_f32_16x16x32_bf16(af[i], bfv[j], acc[i][j], 0,0,0);
    }
#undef STAGE_M

    #pragma unroll
    for (int i=0;i<4;i++){
        #pragma unroll
        for (int j=0;j<4;j++){
            int col = col0 + wc*64 + j*16 + l15;
            float bb = bias[col];
            #pragma unroll
            for (int r=0;r<4;r++){
                int row = row0 + wr*64 + i*16 + lh*4 + r;
                C[(size_t)row*N + col] = f2bf(gelu_tanh(acc[i][j][r] + bb));
            }
        }
    }
}

// ---------------------------------------------------------------- MFMA GEMM 64x64, 3-buf counted-vmcnt: x[M,256] += A@Bt^T + bias (+head)
template<int HEAD>
__launch_bounds__(256)
__global__ void mgemm64_kernel(const u16* __restrict__ A, const u16* __restrict__ Bt,
                               const float* __restrict__ bias, float* __restrict__ x,
                               const float* __restrict__ out_W, const float* __restrict__ out_b,
                               const float* __restrict__ crit_W, const float* __restrict__ crit_b,
                               float* __restrict__ out, int K)
{
    __shared__ u16 As[3][64][32];
    __shared__ u16 Bs[3][64][32];
    int tid = threadIdx.x;
    int wid = tid >> 6, lane = tid & 63;
    int wr = wid >> 1, wc = wid & 1;            // wave tile 32x32
    int row0 = blockIdx.y*64, col0 = blockIdx.x*64;
    int l15 = lane & 15, lh = lane >> 4;

    const u16* Ag = A  + (size_t)(row0 + wid*16 + (lane>>2))*K + (lane&3)*8;
    const u16* Bg = Bt + (size_t)(col0 + wid*16 + (lane>>2))*K + (lane&3)*8;

#define STAGE_S(buf, k0) do{ \
    GLOAD16(Ag + (k0), &As[buf][wid*16][0]); \
    GLOAD16(Bg + (k0), &Bs[buf][wid*16][0]); }while(0)

    f32x4 acc[2][2] = {};
    int nk = K >> 5;
    STAGE_S(0, 0);
    STAGE_S(1, 32);
    for (int kt = 0; kt < nk; kt++){
        int cur = kt % 3;
        if (kt+1 < nk) VMWAIT(2);
        else           VMWAIT(0);
        __builtin_amdgcn_s_barrier();
        bf16x8 af[2], bfv[2];
        #pragma unroll
        for (int i=0;i<2;i++)
            af[i] = *(const bf16x8*)&As[cur][wr*32 + i*16 + l15][lh*8];
        #pragma unroll
        for (int j=0;j<2;j++)
            bfv[j] = *(const bf16x8*)&Bs[cur][wc*32 + j*16 + l15][lh*8];
        if (kt+2 < nk) STAGE_S((kt+2)%3, (kt+2)*32);
        #pragma unroll
        for (int i=0;i<2;i++)
            #pragma unroll
            for (int j=0;j<2;j++)
                acc[i][j] = __builtin_amdgcn_mfma_f32_16x16x32_bf16(af[i], bfv[j], acc[i][j], 0,0,0);
    }
#undef STAGE_S

    #pragma unroll
    for (int i=0;i<2;i++){
        #pragma unroll
        for (int r=0;r<4;r++){
            int row = row0 + wr*32 + i*16 + lh*4 + r;
            float hp = 0.f;
            int s = row & 1023;
            #pragma unroll
            for (int j=0;j<2;j++){
                int col = col0 + wc*32 + j*16 + l15;
                size_t idx = (size_t)row*DD + col;
                float v = acc[i][j][r] + bias[col] + x[idx];
                x[idx] = v;
                if (HEAD){
                    float w = (s == 1023) ? crit_W[col] : out_W[col];
                    hp = fmaf(v, w, hp);
                }
            }
            if (HEAD && s >= 1 + NUM_PM){
                hp += __shfl_xor(hp, 1);
                hp += __shfl_xor(hp, 2);
                hp += __shfl_xor(hp, 4);
                hp += __shfl_xor(hp, 8);
                if (l15 == 0){
                    int b = row >> 10;
                    int jj = (s == 1023) ? 768 : (s - (1 + NUM_PM));
                    float add = hp;
                    if (blockIdx.x == 0 && wc == 0)
                        add += (s == 1023) ? crit_b[0] : out_b[0];
                    atomicAdd(&out[b*769 + jj], add);
                }
            }
        }
    }
}

// ---------------------------------------------------------------- attention: wave per query, precomputed padded member rows
__launch_bounds__(256)
__global__ void attn_kernel(const u16* __restrict__ qkv,
                            const int* __restrict__ pcnt, const int* __restrict__ pmem,
                            const int* __restrict__ poff, const int* __restrict__ kmem,
                            u16* __restrict__ o)
{
    int gq = blockIdx.x*4 + (threadIdx.x >> 6);
    int lane = threadIdx.x & 63;
    int b = gq >> 10, s = gq & 1023;
    const float scale = 0.17677669529663687f;       // 1/sqrt(32)

    if (s == 0 || s == SEQQ-1){
        const u16* vrow = qkv + (size_t)gq*768 + 512 + lane*4;
        *(short4*)(o + (size_t)gq*DD + lane*4) = *(const short4*)vrow;
        return;
    }

    const u16* qb = qkv + (size_t)gq*768 + lane*4;
    short4 q4i = *(const short4*)qb;
    float qx = bf2f((u16)q4i.x)*scale, qy = bf2f((u16)q4i.y)*scale,
          qz = bf2f((u16)q4i.z)*scale, qw = bf2f((u16)q4i.w)*scale;

    int cnt = pcnt[gq];
    const int4* prow = (const int4*)&pmem[(size_t)gq*16];
    int4 m0 = prow[0], m1 = prow[1], m2 = prow[2], m3 = prow[3];

    float m_run = -1e30f, l_run = 0.f;
    float ax=0.f, ay=0.f, az=0.f, aw=0.f;

#define ACHUNK(BASE, MV) do{                                              \
    if ((BASE) < cnt){                                                    \
        short4 k4[4], v4[4];                                              \
        const int mi0=(MV).x, mi1=(MV).y, mi2=(MV).z, mi3=(MV).w;         \
        const u16* kb0 = qkv + (size_t)(b*SEQQ + mi0)*768 + 256 + lane*4; \
        const u16* kb1 = qkv + (size_t)(b*SEQQ + mi1)*768 + 256 + lane*4; \
        const u16* kb2 = qkv + (size_t)(b*SEQQ + mi2)*768 + 256 + lane*4; \
        const u16* kb3 = qkv + (size_t)(b*SEQQ + mi3)*768 + 256 + lane*4; \
        k4[0]=*(const short4*)kb0; v4[0]=*(const short4*)(kb0+256);       \
        k4[1]=*(const short4*)kb1; v4[1]=*(const short4*)(kb1+256);       \
        k4[2]=*(const short4*)kb2; v4[2]=*(const short4*)(kb2+256);       \
        k4[3]=*(const short4*)kb3; v4[3]=*(const short4*)(kb3+256);       \
        _Pragma("unroll")                                                 \
        for (int k=0;k<4;k++){                                            \
            if ((BASE) + k < cnt){                                        \
                float sc = qx*bf2f((u16)k4[k].x) + qy*bf2f((u16)k4[k].y)  \
                         + qz*bf2f((u16)k4[k].z) + qw*bf2f((u16)k4[k].w); \
                sc += __shfl_xor(sc, 1);                                  \
                sc += __shfl_xor(sc, 2);                                  \
                sc += __shfl_xor(sc, 4);                                  \
                float mn = fmaxf(m_run, sc);                              \
                float corr = __expf(m_run - mn);                          \
                float p = __expf(sc - mn);                                \
                l_run = l_run*corr + p;                                   \
                ax = ax*corr + p*bf2f((u16)v4[k].x);                      \
                ay = ay*corr + p*bf2f((u16)v4[k].y);                      \
                az = az*corr + p*bf2f((u16)v4[k].z);                      \
                aw = aw*corr + p*bf2f((u16)v4[k].w);                      \
                m_run = mn;                                               \
            }                                                             \
        }                                                                 \
    } }while(0)

    if (cnt <= 16){
        ACHUNK(0,  m0);
        ACHUNK(4,  m1);
        ACHUNK(8,  m2);
        ACHUNK(12, m3);
    } else {
        const int* klist = kmem + poff[gq];
        for (int j0 = 0; j0 < cnt; j0 += 4){
            short4 k4[4], v4[4];
            #pragma unroll
            for (int k=0;k<4;k++){
                int jj = j0 + k; jj = (jj < cnt) ? jj : (cnt-1);
                int mi = klist[jj];
                const u16* kb = qkv + (size_t)(b*SEQQ + mi)*768 + 256 + lane*4;
                k4[k] = *(const short4*)kb;
                v4[k] = *(const short4*)(kb + 256);
            }
            #pragma unroll
            for (int k=0;k<4;k++){
                if (j0 + k < cnt){
                    float sc = qx*bf2f((u16)k4[k].x) + qy*bf2f((u16)k4[k].y)
                             + qz*bf2f((u16)k4[k].z) + qw*bf2f((u16)k4[k].w);
                    sc += __shfl_xor(sc, 1);
                    sc += __shfl_xor(sc, 2);
                    sc += __shfl_xor(sc, 4);
                    float mn = fmaxf(m_run, sc);
                    float corr = __expf(m_run - mn);
                    float p = __expf(sc - mn);
                    l_run = l_run*corr + p;
                    ax = ax*corr + p*bf2f((u16)v4[k].x);
                    ay = ay*corr + p*bf2f((u16)v4[k].y);
                    az = az*corr + p*bf2f((u16)v4[k].z);
                    aw = aw*corr + p*bf2f((u16)v4[k].w);
                    m_run = mn;
                }
            }
        }
    }
#undef ACHUNK

    float inv = (l_run > 0.f) ? 1.0f/l_run : 0.f;
    u16* orow = o + (size_t)gq*DD + lane*4;
    short4 outv;
    outv.x = (short)f2bf(ax*inv); outv.y = (short)f2bf(ay*inv);
    outv.z = (short)f2bf(az*inv); outv.w = (short)f2bf(aw*inv);
    *(short4*)orow = outv;
}

// ---------------------------------------------------------------- launch
extern "C" void kernel_launch(void* const* d_in, const int* in_sizes, int n_in,
                              void* d_out, int out_size, void* d_ws, size_t ws_size,
                              hipStream_t stream)
{
    const float* vm_states = (const float*)d_in[0];
    const float* num_step  = (const float*)d_in[1];
    const float* pm_states = (const float*)d_in[2];
    const int*   rel       = (const int*)d_in[3];
    const unsigned char* mask = (const unsigned char*)d_in[4];
    const float* pm_W = (const float*)d_in[5];
    const float* pm_b = (const float*)d_in[6];
    const float* vm_W = (const float*)d_in[7];
    const float* vm_b = (const float*)d_in[8];
    const float* Wqkv = (const float*)d_in[9];
    const float* bqkv = (const float*)d_in[10];
    const float* Wo   = (const float*)d_in[11];
    const float* bo   = (const float*)d_in[12];
    const float* ln1g = (const float*)d_in[13];
    const float* ln1b = (const float*)d_in[14];
    const float* ln2g = (const float*)d_in[15];
    const float* ln2b = (const float*)d_in[16];
    const float* W1   = (const float*)d_in[17];
    const float* b1   = (const float*)d_in[18];
    const float* W2   = (const float*)d_in[19];
    const float* b2   = (const float*)d_in[20];
    const float* out_W = (const float*)d_in[21];
    const float* out_b = (const float*)d_in[22];
    const float* crit_W = (const float*)d_in[23];
    const float* crit_b = (const float*)d_in[24];

    char* ws = (char*)d_ws;
    const size_t MB = 1024*1024;
    float* x    = (float*)(ws);                      // [8192][256] f32   :  0..8 MB
    u16*   hbuf = (u16*)(ws + 8*MB);                 // [8192][256] bf16  :  8..12
    u16*   aout = (u16*)(ws + 12*MB);                // [8192][256] bf16  : 12..16
    u16*   qkv  = (u16*)(ws + 16*MB);                // [8192][768] bf16  : 16..28
    u16*   ff1  = (u16*)(ws + 28*MB);                // [8192][1024] bf16 : 28..44
    u16*   wq   = (u16*)(ws + 44*MB);                // [3][768][256]
    u16*   wo   = wq + (size_t)3*768*256;            // [3][256][256]
    u16*   w1   = wo + (size_t)3*256*256;            // [3][1024][256]
    u16*   w2   = w1 + (size_t)3*1024*256;           // [3][256][1024]
    int*   kcnt = (int*)(ws + 50*MB);                // [8][256]
    int*   koff = kcnt + NB*256;                     // [8][256]
    int*   kmem = koff + NB*256;                     // [8][1024]
    int*   pcnt = kmem + NB*SEQQ;                    // [8192]
    int*   poff = pcnt + MROWS;                      // [8192]
    int*   pmem = poff + MROWS;                      // [8192][16]

    prologue_kernel<<<4360, 256, 0, stream>>>(Wqkv, Wo, W1, W2, wq, wo, w1, w2,
                                              rel, mask, kcnt, koff, kmem, pcnt, poff, pmem,
                                              vm_states, num_step, pm_states,
                                              pm_W, pm_b, vm_W, vm_b,
                                              ln1g, ln1b, x, hbuf, (float*)d_out);
    for (int i=0;i<3;i++){
        qgemm_kernel<<<dim3(768/128, MROWS/64),256,0,stream>>>(
            hbuf, wq + (size_t)i*768*256, bqkv + i*768, qkv, 768, 256);
        attn_kernel<<<MROWS/4, 256, 0, stream>>>(qkv, pcnt, pmem, poff, kmem, aout);
        mgemm64_kernel<0><<<dim3(256/64, MROWS/64),256,0,stream>>>(
            aout, wo + (size_t)i*256*256, bo + i*DD, x,
            nullptr, nullptr, nullptr, nullptr, nullptr, 256);
        ln_kernel<<<MROWS/4,256,0,stream>>>(x, ln2g + i*DD, ln2b + i*DD, hbuf);
        mgemm_kernel<<<dim3(1024/128, MROWS/128),256,0,stream>>>(
            hbuf, w1 + (size_t)i*1024*256, b1 + i*FF, ff1, 1024, 256);
        if (i < 2){
            mgemm64_kernel<0><<<dim3(256/64, MROWS/64),256,0,stream>>>(
                ff1, w2 + (size_t)i*256*1024, b2 + i*DD, x,
                nullptr, nullptr, nullptr, nullptr, nullptr, 1024);
            ln_kernel<<<MROWS/4,256,0,stream>>>(x, ln1g + (i+1)*DD, ln1b + (i+1)*DD, hbuf);
        } else {
            mgemm64_kernel<1><<<dim3(256/64, MROWS/64),256,0,stream>>>(
                ff1, w2 + (size_t)i*256*1024, b2 + i*DD, x,
                out_W, out_b, crit_W, crit_b, (float*)d_out, 1024);
        }
    }
}

// Round 12
// 318.412 us; speedup vs baseline: 1.4178x; 1.0203x over previous
//
#include <hip/hip_runtime.h>
#include <hip/hip_bf16.h>
#include <math.h>

#define NUM_PM 254
#define NUM_VM 768
#define SEQQ   1024      // NUM_PM + NUM_VM + 2
#define NH     8
#define DD     256
#define DH     32
#define FF     1024
#define NB     8
#define MROWS  (NB*SEQQ) // 8192

typedef unsigned short u16;
typedef __attribute__((ext_vector_type(8))) short bf16x8;
typedef __attribute__((ext_vector_type(4))) float f32x4;

__device__ __forceinline__ float bf2f(u16 u){
    union { float f; unsigned int i; } c; c.i = ((unsigned int)u) << 16; return c.f;
}
__device__ __forceinline__ u16 f2bf(float f){
    union { float f; unsigned int u; } c; c.f = f;
    unsigned int r = c.u + 0x7FFFu + ((c.u >> 16) & 1u);   // RNE
    return (u16)(r >> 16);
}
__device__ __forceinline__ float gelu_tanh(float x){
    float x3 = x*x*x;
    float t = tanhf(0.7978845608028654f*(x + 0.044715f*x3));
    return 0.5f*x*(1.0f+t);
}

#define GLOAD16(gp, lp) __builtin_amdgcn_global_load_lds( \
    (const __attribute__((address_space(1))) void*)(gp), \
    (__attribute__((address_space(3))) void*)(lp), 16, 0, 0)

// ---------------------------------------------------------------- prologue:
// tcast (0..2303) | group build + pq tables + out-zero (2304..2311) | embed+LN1 (2312..4359)
__global__ void prologue_kernel(const float* __restrict__ Wqkv, const float* __restrict__ Wo,
                                const float* __restrict__ W1,   const float* __restrict__ W2,
                                u16* __restrict__ wq, u16* __restrict__ wo,
                                u16* __restrict__ w1, u16* __restrict__ w2,
                                const int* __restrict__ rel, const unsigned char* __restrict__ mask,
                                int* __restrict__ kcnt, int* __restrict__ koff, int* __restrict__ kmem,
                                int* __restrict__ pcnt, int* __restrict__ poff, int* __restrict__ pmem,
                                const float* __restrict__ vm_states,
                                const float* __restrict__ num_step,
                                const float* __restrict__ pm_states,
                                const float* __restrict__ pm_W, const float* __restrict__ pm_b,
                                const float* __restrict__ vm_W, const float* __restrict__ vm_b,
                                const float* __restrict__ g, const float* __restrict__ beta,
                                float* __restrict__ x, u16* __restrict__ h,
                                float* __restrict__ outz)
{
    __shared__ float t[32][33];
    __shared__ int cntS[256], offS[256], wsum4[4];
    __shared__ int memS[1040];
    int bid = blockIdx.x;
    int tid = threadIdx.x;
    if (bid < 2304){
        // ---- transpose-cast one 32x32 tile
        int id = bid;
        const float* in; u16* out; int K, N, layer, tile;
        if (id < 576)       { in=Wqkv; out=wq; K=256;  N=768;  layer=id/192; tile=id%192; }
        else if (id < 768)  { id-=576;  in=Wo; out=wo; K=256;  N=256;  layer=id/64;  tile=id%64;  }
        else if (id < 1536) { id-=768;  in=W1; out=w1; K=256;  N=1024; layer=id/256; tile=id%256; }
        else                { id-=1536; in=W2; out=w2; K=1024; N=256;  layer=id/256; tile=id%256; }
        int ntx = N/32;
        int n0 = (tile % ntx)*32, k0 = (tile / ntx)*32;
        size_t lofs = (size_t)layer * K * N;
        int tx = tid & 31, ty = tid >> 5;
        #pragma unroll
        for (int i=0;i<4;i++)
            t[ty + i*8][tx] = in[lofs + (size_t)(k0 + ty + i*8)*N + n0 + tx];
        __syncthreads();
        #pragma unroll
        for (int i=0;i<4;i++)
            out[lofs + (size_t)(n0 + ty + i*8)*K + k0 + tx] = f2bf(t[tx][ty + i*8]);
    } else if (bid < 2312){
        // ---- group build for batch b (counting sort of valid keys by code) + pq tables
        int b = bid - 2304;
        cntS[tid] = 0;
        __syncthreads();
        int myc[4], myp[4];
        bool mykey[4];
        #pragma unroll
        for (int si=0; si<4; si++){
            int s = si*256 + tid;
            bool mid = (s != 0) && (s != SEQQ-1);
            myc[si] = -1; mykey[si] = false;
            if (mid){
                int cc = rel[b*(SEQQ-2) + s-1];
                myc[si] = cc;
                bool masked = (s >= 1+NUM_PM) && mask[b*NUM_VM + (s-1-NUM_PM)];
                if (!masked){ mykey[si] = true; myp[si] = atomicAdd(&cntS[cc], 1); }
            }
        }
        __syncthreads();
        {
            int v = cntS[tid];
            int incl = v;
            #pragma unroll
            for (int d=1; d<64; d<<=1){
                int n = __shfl_up(incl, d);
                if ((tid & 63) >= d) incl += n;
            }
            offS[tid] = incl - v;
            if ((tid & 63) == 63) wsum4[tid>>6] = incl;
        }
        __syncthreads();
        {
            int w = tid >> 6, base = 0;
            #pragma unroll
            for (int i=0;i<4;i++) if (i < w) base += wsum4[i];
            offS[tid] += base;
        }
        __syncthreads();
        #pragma unroll
        for (int si=0; si<4; si++){
            if (mykey[si]){
                int s = si*256 + tid;
                int pos = offS[myc[si]] + myp[si];
                memS[pos] = s;
                kmem[b*SEQQ + pos] = s;
            }
        }
        kcnt[b*256 + tid] = cntS[tid];
        koff[b*256 + tid] = offS[tid];
        __syncthreads();     // memS visible to all
        // per-query padded member rows
        #pragma unroll
        for (int si=0; si<4; si++){
            int s = si*256 + tid;
            if (myc[si] >= 0){
                int c = myc[si];
                int cnt = cntS[c], off = offS[c];
                pcnt[b*SEQQ + s] = cnt;
                poff[b*SEQQ + s] = b*SEQQ + off;
                int mrow[16];
                #pragma unroll
                for (int j=0;j<16;j++)
                    mrow[j] = (j < cnt) ? memS[off + j] : s;   // pad with self (safe addr)
                int4* prow = (int4*)&pmem[(size_t)(b*SEQQ + s)*16];
                prow[0] = (int4){mrow[0], mrow[1], mrow[2], mrow[3]};
                prow[1] = (int4){mrow[4], mrow[5], mrow[6], mrow[7]};
                prow[2] = (int4){mrow[8], mrow[9], mrow[10],mrow[11]};
                prow[3] = (int4){mrow[12],mrow[13],mrow[14],mrow[15]};
            }
        }
        // zero the 769 outputs of this batch (head uses atomicAdd)
        #pragma unroll
        for (int si=0; si<4; si++){
            int idx = si*256 + tid;
            if (idx < 769) outz[b*769 + idx] = 0.f;
        }
    } else {
        // ---- embed + LN1(layer0): wave per row
        int row = (bid - 2312)*4 + (tid>>6);
        int lane = tid & 63;
        int b = row >> 10, s = row & 1023;
        int col = lane*4;
        float4 out;
        if (s == 0){
            float v = num_step[b]; out = (float4){v,v,v,v};
        } else if (s == SEQQ-1){
            out = (float4){-1.f,-1.f,-1.f,-1.f};
        } else {
            const float* in; const float* W; const float* bias;
            if (s <= NUM_PM){ in = pm_states + (size_t)(b*NUM_PM + s-1)*16; W = pm_W; bias = pm_b; }
            else            { in = vm_states + (size_t)(b*NUM_VM + (s-1-NUM_PM))*16; W = vm_W; bias = vm_b; }
            float4 i0 = *(const float4*)in,      i1 = *(const float4*)(in+4);
            float4 i2 = *(const float4*)(in+8),  i3 = *(const float4*)(in+12);
            float in16[16] = {i0.x,i0.y,i0.z,i0.w, i1.x,i1.y,i1.z,i1.w,
                              i2.x,i2.y,i2.z,i2.w, i3.x,i3.y,i3.z,i3.w};
            out = *(const float4*)&bias[col];
            #pragma unroll
            for (int k=0;k<16;k++){
                float4 w4 = *(const float4*)&W[k*DD + col];
                out.x = fmaf(in16[k], w4.x, out.x);
                out.y = fmaf(in16[k], w4.y, out.y);
                out.z = fmaf(in16[k], w4.z, out.z);
                out.w = fmaf(in16[k], w4.w, out.w);
            }
        }
        *(float4*)&x[(size_t)row*DD + col] = out;
        float s1 = out.x+out.y+out.z+out.w;
        float s2 = fmaf(out.x,out.x, fmaf(out.y,out.y, fmaf(out.z,out.z, out.w*out.w)));
        #pragma unroll
        for (int off=1; off<64; off<<=1){ s1 += __shfl_xor(s1,off); s2 += __shfl_xor(s2,off); }
        float m    = s1*(1.0f/DD);
        float var  = s2*(1.0f/DD) - m*m;
        float rstd = rsqrtf(var + 1e-5f);
        float4 g4 = *(const float4*)&g[col];
        float4 b4 = *(const float4*)&beta[col];
        short4 o;
        o.x = (short)f2bf((out.x-m)*rstd*g4.x + b4.x);
        o.y = (short)f2bf((out.y-m)*rstd*g4.y + b4.y);
        o.z = (short)f2bf((out.z-m)*rstd*g4.z + b4.z);
        o.w = (short)f2bf((out.w-m)*rstd*g4.w + b4.w);
        *(short4*)&h[(size_t)row*DD + col] = o;
    }
}

// ---------------------------------------------------------------- layernorm: wave per row, f32 in -> bf16 out
__global__ void ln_kernel(const float* __restrict__ x, const float* __restrict__ g,
                          const float* __restrict__ bta, u16* __restrict__ out)
{
    int row = blockIdx.x*4 + (threadIdx.x>>6);
    int lane = threadIdx.x & 63;
    const float4 v = *(const float4*)&x[(size_t)row*DD + lane*4];
    float s1 = v.x+v.y+v.z+v.w;
    float s2 = fmaf(v.x,v.x, fmaf(v.y,v.y, fmaf(v.z,v.z, v.w*v.w)));
    #pragma unroll
    for (int off=1; off<64; off<<=1){ s1 += __shfl_xor(s1,off); s2 += __shfl_xor(s2,off); }
    float m    = s1*(1.0f/DD);
    float var  = s2*(1.0f/DD) - m*m;
    float rstd = rsqrtf(var + 1e-5f);
    float4 g4 = *(const float4*)&g[lane*4];
    float4 b4 = *(const float4*)&bta[lane*4];
    short4 o;
    o.x = (short)f2bf((v.x-m)*rstd*g4.x + b4.x);
    o.y = (short)f2bf((v.y-m)*rstd*g4.y + b4.y);
    o.z = (short)f2bf((v.z-m)*rstd*g4.z + b4.z);
    o.w = (short)f2bf((v.w-m)*rstd*g4.w + b4.w);
    *(short4*)&out[(size_t)row*DD + lane*4] = o;
}

// T4 counted-vmcnt waits: keep prefetched tiles in flight across the barrier.
#define VMWAIT(N) asm volatile("s_waitcnt vmcnt(" #N ")" ::: "memory")

// ---------------------------------------------------------------- MFMA GEMM 64x128, 3-buf counted-vmcnt: C bf16 = A@Bt^T + bias (QKV)
__launch_bounds__(256)
__global__ void qgemm_kernel(const u16* __restrict__ A, const u16* __restrict__ Bt,
                             const float* __restrict__ bias, u16* __restrict__ C,
                             int N, int K)
{
    __shared__ u16 As[3][64][32];
    __shared__ u16 Bs[3][128][32];
    int tid = threadIdx.x;
    int wid = tid >> 6, lane = tid & 63;
    int wr = wid >> 1, wc = wid & 1;            // wave tile 32x64
    int row0 = blockIdx.y*64, col0 = blockIdx.x*128;
    int l15 = lane & 15, lh = lane >> 4;

    const u16* Ag = A  + (size_t)(row0 + wid*16 + (lane>>2))*K + (lane&3)*8;
    const u16* Bg = Bt + (size_t)(col0 + wid*32 + (lane>>2))*K + (lane&3)*8;

#define STAGE_Q(buf, k0) do{ \
    GLOAD16(Ag + (k0),          &As[buf][wid*16][0]);    \
    GLOAD16(Bg + (k0),          &Bs[buf][wid*32][0]);    \
    GLOAD16(Bg + (k0) + 16*K,   &Bs[buf][wid*32+16][0]); }while(0)

    f32x4 acc[2][4] = {};
    int nk = K >> 5;
    STAGE_Q(0, 0);
    STAGE_Q(1, 32);
    for (int kt = 0; kt < nk; kt++){
        int cur = kt % 3;
        if (kt+1 < nk) VMWAIT(3);   // oldest tile done; next tile's 3 loads stay in flight
        else           VMWAIT(0);
        __builtin_amdgcn_s_barrier();
        bf16x8 af[2], bfv[4];
        #pragma unroll
        for (int i=0;i<2;i++)
            af[i] = *(const bf16x8*)&As[cur][wr*32 + i*16 + l15][lh*8];
        #pragma unroll
        for (int j=0;j<4;j++)
            bfv[j] = *(const bf16x8*)&Bs[cur][wc*64 + j*16 + l15][lh*8];
        if (kt+2 < nk) STAGE_Q((kt+2)%3, (kt+2)*32);
        #pragma unroll
        for (int i=0;i<2;i++)
            #pragma unroll
            for (int j=0;j<4;j++)
                acc[i][j] = __builtin_amdgcn_mfma_f32_16x16x32_bf16(af[i], bfv[j], acc[i][j], 0,0,0);
    }
#undef STAGE_Q

    #pragma unroll
    for (int i=0;i<2;i++){
        #pragma unroll
        for (int j=0;j<4;j++){
            int col = col0 + wc*64 + j*16 + l15;
            float bb = bias[col];
            #pragma unroll
            for (int r=0;r<4;r++){
                int row = row0 + wr*32 + i*16 + lh*4 + r;
                C[(size_t)row*N + col] = f2bf(acc[i][j][r] + bb);
            }
        }
    }
}

// ---------------------------------------------------------------- MFMA GEMM 128x128, 3-buf counted-vmcnt: C bf16 = gelu(A@Bt^T + bias) (FF1)
__launch_bounds__(256)
__global__ void mgemm_kernel(const u16* __restrict__ A, const u16* __restrict__ Bt,
                             const float* __restrict__ bias, u16* __restrict__ C,
                             int N, int K)
{
    __shared__ u16 As[3][128][32];
    __shared__ u16 Bs[3][128][32];
    int tid = threadIdx.x;
    int wid = tid >> 6, lane = tid & 63;
    int wr = wid >> 1, wc = wid & 1;
    int row0 = blockIdx.y*128, col0 = blockIdx.x*128;
    int l15 = lane & 15, lh = lane >> 4;

    const u16* Ag = A  + (size_t)(row0 + wid*32 + (lane>>2))*K + (lane&3)*8;
    const u16* Bg = Bt + (size_t)(col0 + wid*32 + (lane>>2))*K + (lane&3)*8;

#define STAGE_M(buf, k0) do{ \
    GLOAD16(Ag + (k0),          &As[buf][wid*32][0]);    \
    GLOAD16(Ag + (k0) + 16*K,   &As[buf][wid*32+16][0]); \
    GLOAD16(Bg + (k0),          &Bs[buf][wid*32][0]);    \
    GLOAD16(Bg + (k0) + 16*K,   &Bs[buf][wid*32+16][0]); }while(0)

    f32x4 acc[4][4] = {};
    int nk = K >> 5;
    STAGE_M(0, 0);
    STAGE_M(1, 32);
    for (int kt = 0; kt < nk; kt++){
        int cur = kt % 3;
        if (kt+1 < nk) VMWAIT(4);
        else           VMWAIT(0);
        __builtin_amdgcn_s_barrier();
        bf16x8 af[4], bfv[4];
        #pragma unroll
        for (int f=0; f<4; f++){
            af[f]  = *(const bf16x8*)&As[cur][wr*64 + f*16 + l15][lh*8];
            bfv[f] = *(const bf16x8*)&Bs[cur][wc*64 + f*16 + l15][lh*8];
        }
        if (kt+2 < nk) STAGE_M((kt+2)%3, (kt+2)*32);
        #pragma unroll
        for (int i=0;i<4;i++)
            #pragma unroll
            for (int j=0;j<4;j++)
                acc[i][j] = __builtin_amdgcn_mfma_f32_16x16x32_bf16(af[i], bfv[j], acc[i][j], 0,0,0);
    }
#undef STAGE_M

    #pragma unroll
    for (int i=0;i<4;i++){
        #pragma unroll
        for (int j=0;j<4;j++){
            int col = col0 + wc*64 + j*16 + l15;
            float bb = bias[col];
            #pragma unroll
            for (int r=0;r<4;r++){
                int row = row0 + wr*64 + i*16 + lh*4 + r;
                C[(size_t)row*N + col] = f2bf(gelu_tanh(acc[i][j][r] + bb));
            }
        }
    }
}

// ---------------------------------------------------------------- MFMA GEMM 64x64, 3-buf counted-vmcnt: x[M,256] += A@Bt^T + bias (+head)
template<int HEAD>
__launch_bounds__(256)
__global__ void mgemm64_kernel(const u16* __restrict__ A, const u16* __restrict__ Bt,
                               const float* __restrict__ bias, float* __restrict__ x,
                               const float* __restrict__ out_W, const float* __restrict__ out_b,
                               const float* __restrict__ crit_W, const float* __restrict__ crit_b,
                               float* __restrict__ out, int K)
{
    __shared__ u16 As[3][64][32];
    __shared__ u16 Bs[3][64][32];
    int tid = threadIdx.x;
    int wid = tid >> 6, lane = tid & 63;
    int wr = wid >> 1, wc = wid & 1;            // wave tile 32x32
    int row0 = blockIdx.y*64, col0 = blockIdx.x*64;
    int l15 = lane & 15, lh = lane >> 4;

    const u16* Ag = A  + (size_t)(row0 + wid*16 + (lane>>2))*K + (lane&3)*8;
    const u16* Bg = Bt + (size_t)(col0 + wid*16 + (lane>>2))*K + (lane&3)*8;

#define STAGE_S(buf, k0) do{ \
    GLOAD16(Ag + (k0), &As[buf][wid*16][0]); \
    GLOAD16(Bg + (k0), &Bs[buf][wid*16][0]); }while(0)

    f32x4 acc[2][2] = {};
    int nk = K >> 5;
    STAGE_S(0, 0);
    STAGE_S(1, 32);
    for (int kt = 0; kt < nk; kt++){
        int cur = kt % 3;
        if (kt+1 < nk) VMWAIT(2);
        else           VMWAIT(0);
        __builtin_amdgcn_s_barrier();
        bf16x8 af[2], bfv[2];
        #pragma unroll
        for (int i=0;i<2;i++)
            af[i] = *(const bf16x8*)&As[cur][wr*32 + i*16 + l15][lh*8];
        #pragma unroll
        for (int j=0;j<2;j++)
            bfv[j] = *(const bf16x8*)&Bs[cur][wc*32 + j*16 + l15][lh*8];
        if (kt+2 < nk) STAGE_S((kt+2)%3, (kt+2)*32);
        #pragma unroll
        for (int i=0;i<2;i++)
            #pragma unroll
            for (int j=0;j<2;j++)
                acc[i][j] = __builtin_amdgcn_mfma_f32_16x16x32_bf16(af[i], bfv[j], acc[i][j], 0,0,0);
    }
#undef STAGE_S

    #pragma unroll
    for (int i=0;i<2;i++){
        #pragma unroll
        for (int r=0;r<4;r++){
            int row = row0 + wr*32 + i*16 + lh*4 + r;
            float hp = 0.f;
            int s = row & 1023;
            #pragma unroll
            for (int j=0;j<2;j++){
                int col = col0 + wc*32 + j*16 + l15;
                size_t idx = (size_t)row*DD + col;
                float v = acc[i][j][r] + bias[col] + x[idx];
                x[idx] = v;
                if (HEAD){
                    float w = (s == 1023) ? crit_W[col] : out_W[col];
                    hp = fmaf(v, w, hp);
                }
            }
            if (HEAD && s >= 1 + NUM_PM){
                hp += __shfl_xor(hp, 1);
                hp += __shfl_xor(hp, 2);
                hp += __shfl_xor(hp, 4);
                hp += __shfl_xor(hp, 8);
                if (l15 == 0){
                    int b = row >> 10;
                    int jj = (s == 1023) ? 768 : (s - (1 + NUM_PM));
                    float add = hp;
                    if (blockIdx.x == 0 && wc == 0)
                        add += (s == 1023) ? crit_b[0] : out_b[0];
                    atomicAdd(&out[b*769 + jj], add);
                }
            }
        }
    }
}

// ---------------------------------------------------------------- attention: wave per query; flat softmax fast path (cnt<=8)
__launch_bounds__(256)
__global__ void attn_kernel(const u16* __restrict__ qkv,
                            const int* __restrict__ pcnt, const int* __restrict__ pmem,
                            const int* __restrict__ poff, const int* __restrict__ kmem,
                            u16* __restrict__ o)
{
    int gq = blockIdx.x*4 + (threadIdx.x >> 6);
    int lane = threadIdx.x & 63;
    int b = gq >> 10, s = gq & 1023;
    const float scale = 0.17677669529663687f;       // 1/sqrt(32)

    if (s == 0 || s == SEQQ-1){
        const u16* vrow = qkv + (size_t)gq*768 + 512 + lane*4;
        *(short4*)(o + (size_t)gq*DD + lane*4) = *(const short4*)vrow;
        return;
    }

    const u16* qb = qkv + (size_t)gq*768 + lane*4;
    short4 q4i = *(const short4*)qb;
    float qx = bf2f((u16)q4i.x)*scale, qy = bf2f((u16)q4i.y)*scale,
          qz = bf2f((u16)q4i.z)*scale, qw = bf2f((u16)q4i.w)*scale;

    int cnt = pcnt[gq];
    const int4* prow = (const int4*)&pmem[(size_t)gq*16];
    int4 m0 = prow[0], m1 = prow[1];

    float l_run = 0.f;
    float ax=0.f, ay=0.f, az=0.f, aw=0.f;

    if (cnt <= 8){
        // ---- flat softmax: batch all loads (1 L2 round trip), no serial rescale chain
        short4 k4[8], v4[8];
#define LKV(J, MI) do{ const u16* kb_ = qkv + (size_t)(b*SEQQ + (MI))*768 + 256 + lane*4; \
        k4[J] = *(const short4*)kb_; v4[J] = *(const short4*)(kb_ + 256); }while(0)
        LKV(0, m0.x); LKV(1, m0.y); LKV(2, m0.z); LKV(3, m0.w);
        LKV(4, m1.x); LKV(5, m1.y); LKV(6, m1.z); LKV(7, m1.w);
#undef LKV
        float sc[8];
        #pragma unroll
        for (int j=0;j<8;j++){
            float d = qx*bf2f((u16)k4[j].x) + qy*bf2f((u16)k4[j].y)
                    + qz*bf2f((u16)k4[j].z) + qw*bf2f((u16)k4[j].w);
            d += __shfl_xor(d, 1);
            d += __shfl_xor(d, 2);
            d += __shfl_xor(d, 4);
            sc[j] = d;
        }
        float mx = -1e30f;
        #pragma unroll
        for (int j=0;j<8;j++) if (j < cnt) mx = fmaxf(mx, sc[j]);
        #pragma unroll
        for (int j=0;j<8;j++){
            if (j < cnt){
                float p = __expf(sc[j] - mx);
                l_run += p;
                ax = fmaf(p, bf2f((u16)v4[j].x), ax);
                ay = fmaf(p, bf2f((u16)v4[j].y), ay);
                az = fmaf(p, bf2f((u16)v4[j].z), az);
                aw = fmaf(p, bf2f((u16)v4[j].w), aw);
            }
        }
    } else {
        int4 m2 = prow[2], m3 = prow[3];
        float m_run = -1e30f;

#define ACHUNK(BASE, MV) do{                                              \
    if ((BASE) < cnt){                                                    \
        short4 k4[4], v4[4];                                              \
        const int mi0=(MV).x, mi1=(MV).y, mi2=(MV).z, mi3=(MV).w;         \
        const u16* kb0 = qkv + (size_t)(b*SEQQ + mi0)*768 + 256 + lane*4; \
        const u16* kb1 = qkv + (size_t)(b*SEQQ + mi1)*768 + 256 + lane*4; \
        const u16* kb2 = qkv + (size_t)(b*SEQQ + mi2)*768 + 256 + lane*4; \
        const u16* kb3 = qkv + (size_t)(b*SEQQ + mi3)*768 + 256 + lane*4; \
        k4[0]=*(const short4*)kb0; v4[0]=*(const short4*)(kb0+256);       \
        k4[1]=*(const short4*)kb1; v4[1]=*(const short4*)(kb1+256);       \
        k4[2]=*(const short4*)kb2; v4[2]=*(const short4*)(kb2+256);       \
        k4[3]=*(const short4*)kb3; v4[3]=*(const short4*)(kb3+256);       \
        _Pragma("unroll")                                                 \
        for (int k=0;k<4;k++){                                            \
            if ((BASE) + k < cnt){                                        \
                float sc = qx*bf2f((u16)k4[k].x) + qy*bf2f((u16)k4[k].y)  \
                         + qz*bf2f((u16)k4[k].z) + qw*bf2f((u16)k4[k].w); \
                sc += __shfl_xor(sc, 1);                                  \
                sc += __shfl_xor(sc, 2);                                  \
                sc += __shfl_xor(sc, 4);                                  \
                float mn = fmaxf(m_run, sc);                              \
                float corr = __expf(m_run - mn);                          \
                float p = __expf(sc - mn);                                \
                l_run = l_run*corr + p;                                   \
                ax = ax*corr + p*bf2f((u16)v4[k].x);                      \
                ay = ay*corr + p*bf2f((u16)v4[k].y);                      \
                az = az*corr + p*bf2f((u16)v4[k].z);                      \
                aw = aw*corr + p*bf2f((u16)v4[k].w);                      \
                m_run = mn;                                               \
            }                                                             \
        }                                                                 \
    } }while(0)

        if (cnt <= 16){
            ACHUNK(0,  m0);
            ACHUNK(4,  m1);
            ACHUNK(8,  m2);
            ACHUNK(12, m3);
        } else {
            const int* klist = kmem + poff[gq];
            for (int j0 = 0; j0 < cnt; j0 += 4){
                short4 k4[4], v4[4];
                #pragma unroll
                for (int k=0;k<4;k++){
                    int jj = j0 + k; jj = (jj < cnt) ? jj : (cnt-1);
                    int mi = klist[jj];
                    const u16* kb = qkv + (size_t)(b*SEQQ + mi)*768 + 256 + lane*4;
                    k4[k] = *(const short4*)kb;
                    v4[k] = *(const short4*)(kb + 256);
                }
                #pragma unroll
                for (int k=0;k<4;k++){
                    if (j0 + k < cnt){
                        float sc = qx*bf2f((u16)k4[k].x) + qy*bf2f((u16)k4[k].y)
                                 + qz*bf2f((u16)k4[k].z) + qw*bf2f((u16)k4[k].w);
                        sc += __shfl_xor(sc, 1);
                        sc += __shfl_xor(sc, 2);
                        sc += __shfl_xor(sc, 4);
                        float mn = fmaxf(m_run, sc);
                        float corr = __expf(m_run - mn);
                        float p = __expf(sc - mn);
                        l_run = l_run*corr + p;
                        ax = ax*corr + p*bf2f((u16)v4[k].x);
                        ay = ay*corr + p*bf2f((u16)v4[k].y);
                        az = az*corr + p*bf2f((u16)v4[k].z);
                        aw = aw*corr + p*bf2f((u16)v4[k].w);
                        m_run = mn;
                    }
                }
            }
        }
#undef ACHUNK
    }

    float inv = (l_run > 0.f) ? 1.0f/l_run : 0.f;
    u16* orow = o + (size_t)gq*DD + lane*4;
    short4 outv;
    outv.x = (short)f2bf(ax*inv); outv.y = (short)f2bf(ay*inv);
    outv.z = (short)f2bf(az*inv); outv.w = (short)f2bf(aw*inv);
    *(short4*)orow = outv;
}

// ---------------------------------------------------------------- launch
extern "C" void kernel_launch(void* const* d_in, const int* in_sizes, int n_in,
                              void* d_out, int out_size, void* d_ws, size_t ws_size,
                              hipStream_t stream)
{
    const float* vm_states = (const float*)d_in[0];
    const float* num_step  = (const float*)d_in[1];
    const float* pm_states = (const float*)d_in[2];
    const int*   rel       = (const int*)d_in[3];
    const unsigned char* mask = (const unsigned char*)d_in[4];
    const float* pm_W = (const float*)d_in[5];
    const float* pm_b = (const float*)d_in[6];
    const float* vm_W = (const float*)d_in[7];
    const float* vm_b = (const float*)d_in[8];
    const float* Wqkv = (const float*)d_in[9];
    const float* bqkv = (const float*)d_in[10];
    const float* Wo   = (const float*)d_in[11];
    const float* bo   = (const float*)d_in[12];
    const float* ln1g = (const float*)d_in[13];
    const float* ln1b = (const float*)d_in[14];
    const float* ln2g = (const float*)d_in[15];
    const float* ln2b = (const float*)d_in[16];
    const float* W1   = (const float*)d_in[17];
    const float* b1   = (const float*)d_in[18];
    const float* W2   = (const float*)d_in[19];
    const float* b2   = (const float*)d_in[20];
    const float* out_W = (const float*)d_in[21];
    const float* out_b = (const float*)d_in[22];
    const float* crit_W = (const float*)d_in[23];
    const float* crit_b = (const float*)d_in[24];

    char* ws = (char*)d_ws;
    const size_t MB = 1024*1024;
    float* x    = (float*)(ws);                      // [8192][256] f32   :  0..8 MB
    u16*   hbuf = (u16*)(ws + 8*MB);                 // [8192][256] bf16  :  8..12
    u16*   aout = (u16*)(ws + 12*MB);                // [8192][256] bf16  : 12..16
    u16*   qkv  = (u16*)(ws + 16*MB);                // [8192][768] bf16  : 16..28
    u16*   ff1  = (u16*)(ws + 28*MB);                // [8192][1024] bf16 : 28..44
    u16*   wq   = (u16*)(ws + 44*MB);                // [3][768][256]
    u16*   wo   = wq + (size_t)3*768*256;            // [3][256][256]
    u16*   w1   = wo + (size_t)3*256*256;            // [3][1024][256]
    u16*   w2   = w1 + (size_t)3*1024*256;           // [3][256][1024]
    int*   kcnt = (int*)(ws + 50*MB);                // [8][256]
    int*   koff = kcnt + NB*256;                     // [8][256]
    int*   kmem = koff + NB*256;                     // [8][1024]
    int*   pcnt = kmem + NB*SEQQ;                    // [8192]
    int*   poff = pcnt + MROWS;                      // [8192]
    int*   pmem = poff + MROWS;                      // [8192][16]

    prologue_kernel<<<4360, 256, 0, stream>>>(Wqkv, Wo, W1, W2, wq, wo, w1, w2,
                                              rel, mask, kcnt, koff, kmem, pcnt, poff, pmem,
                                              vm_states, num_step, pm_states,
                                              pm_W, pm_b, vm_W, vm_b,
                                              ln1g, ln1b, x, hbuf, (float*)d_out);
    for (int i=0;i<3;i++){
        qgemm_kernel<<<dim3(768/128, MROWS/64),256,0,stream>>>(
            hbuf, wq + (size_t)i*768*256, bqkv + i*768, qkv, 768, 256);
        attn_kernel<<<MROWS/4, 256, 0, stream>>>(qkv, pcnt, pmem, poff, kmem, aout);
        mgemm64_kernel<0><<<dim3(256/64, MROWS/64),256,0,stream>>>(
            aout, wo + (size_t)i*256*256, bo + i*DD, x,
            nullptr, nullptr, nullptr, nullptr, nullptr, 256);
        ln_kernel<<<MROWS/4,256,0,stream>>>(x, ln2g + i*DD, ln2b + i*DD, hbuf);
        mgemm_kernel<<<dim3(1024/128, MROWS/128),256,0,stream>>>(
            hbuf, w1 + (size_t)i*1024*256, b1 + i*FF, ff1, 1024, 256);
        if (i < 2){
            mgemm64_kernel<0><<<dim3(256/64, MROWS/64),256,0,stream>>>(
                ff1, w2 + (size_t)i*256*1024, b2 + i*DD, x,
                nullptr, nullptr, nullptr, nullptr, nullptr, 1024);
            ln_kernel<<<MROWS/4,256,0,stream>>>(x, ln1g + (i+1)*DD, ln1b + (i+1)*DD, hbuf);
        } else {
            mgemm64_kernel<1><<<dim3(256/64, MROWS/64),256,0,stream>>>(
                ff1, w2 + (size_t)i*256*1024, b2 + i*DD, x,
                out_W, out_b, crit_W, crit_b, (float*)d_out, 1024);
        }
    }
}

// Round 13
// 314.356 us; speedup vs baseline: 1.4361x; 1.0129x over previous
//
#include <hip/hip_runtime.h>
#include <hip/hip_bf16.h>
#include <math.h>

#define NUM_PM 254
#define NUM_VM 768
#define SEQQ   1024      // NUM_PM + NUM_VM + 2
#define NH     8
#define DD     256
#define DH     32
#define FF     1024
#define NB     8
#define MROWS  (NB*SEQQ) // 8192

typedef unsigned short u16;
typedef __attribute__((ext_vector_type(8))) short bf16x8;
typedef __attribute__((ext_vector_type(4))) float f32x4;

__device__ __forceinline__ float bf2f(u16 u){
    union { float f; unsigned int i; } c; c.i = ((unsigned int)u) << 16; return c.f;
}
__device__ __forceinline__ u16 f2bf(float f){
    union { float f; unsigned int u; } c; c.f = f;
    unsigned int r = c.u + 0x7FFFu + ((c.u >> 16) & 1u);   // RNE
    return (u16)(r >> 16);
}
__device__ __forceinline__ float gelu_tanh(float x){
    float x3 = x*x*x;
    float t = tanhf(0.7978845608028654f*(x + 0.044715f*x3));
    return 0.5f*x*(1.0f+t);
}

#define GLOAD16(gp, lp) __builtin_amdgcn_global_load_lds( \
    (const __attribute__((address_space(1))) void*)(gp), \
    (__attribute__((address_space(3))) void*)(lp), 16, 0, 0)

// ---------------------------------------------------------------- prologue:
// tcast (0..2303) | group build + pq tables + out-zero (2304..2311) | embed+LN1 (2312..4359)
__global__ void prologue_kernel(const float* __restrict__ Wqkv, const float* __restrict__ Wo,
                                const float* __restrict__ W1,   const float* __restrict__ W2,
                                u16* __restrict__ wq, u16* __restrict__ wo,
                                u16* __restrict__ w1, u16* __restrict__ w2,
                                const int* __restrict__ rel, const unsigned char* __restrict__ mask,
                                int* __restrict__ kcnt, int* __restrict__ koff, int* __restrict__ kmem,
                                int* __restrict__ pcnt, int* __restrict__ poff, int* __restrict__ pmem,
                                const float* __restrict__ vm_states,
                                const float* __restrict__ num_step,
                                const float* __restrict__ pm_states,
                                const float* __restrict__ pm_W, const float* __restrict__ pm_b,
                                const float* __restrict__ vm_W, const float* __restrict__ vm_b,
                                const float* __restrict__ g, const float* __restrict__ beta,
                                float* __restrict__ x, u16* __restrict__ h,
                                float* __restrict__ outz)
{
    __shared__ float t[32][33];
    __shared__ int cntS[256], offS[256], wsum4[4];
    __shared__ int memS[1040];
    int bid = blockIdx.x;
    int tid = threadIdx.x;
    if (bid < 2304){
        // ---- transpose-cast one 32x32 tile
        int id = bid;
        const float* in; u16* out; int K, N, layer, tile;
        if (id < 576)       { in=Wqkv; out=wq; K=256;  N=768;  layer=id/192; tile=id%192; }
        else if (id < 768)  { id-=576;  in=Wo; out=wo; K=256;  N=256;  layer=id/64;  tile=id%64;  }
        else if (id < 1536) { id-=768;  in=W1; out=w1; K=256;  N=1024; layer=id/256; tile=id%256; }
        else                { id-=1536; in=W2; out=w2; K=1024; N=256;  layer=id/256; tile=id%256; }
        int ntx = N/32;
        int n0 = (tile % ntx)*32, k0 = (tile / ntx)*32;
        size_t lofs = (size_t)layer * K * N;
        int tx = tid & 31, ty = tid >> 5;
        #pragma unroll
        for (int i=0;i<4;i++)
            t[ty + i*8][tx] = in[lofs + (size_t)(k0 + ty + i*8)*N + n0 + tx];
        __syncthreads();
        #pragma unroll
        for (int i=0;i<4;i++)
            out[lofs + (size_t)(n0 + ty + i*8)*K + k0 + tx] = f2bf(t[tx][ty + i*8]);
    } else if (bid < 2312){
        // ---- group build for batch b (counting sort of valid keys by code) + pq tables
        int b = bid - 2304;
        cntS[tid] = 0;
        __syncthreads();
        int myc[4], myp[4];
        bool mykey[4];
        #pragma unroll
        for (int si=0; si<4; si++){
            int s = si*256 + tid;
            bool mid = (s != 0) && (s != SEQQ-1);
            myc[si] = -1; mykey[si] = false;
            if (mid){
                int cc = rel[b*(SEQQ-2) + s-1];
                myc[si] = cc;
                bool masked = (s >= 1+NUM_PM) && mask[b*NUM_VM + (s-1-NUM_PM)];
                if (!masked){ mykey[si] = true; myp[si] = atomicAdd(&cntS[cc], 1); }
            }
        }
        __syncthreads();
        {
            int v = cntS[tid];
            int incl = v;
            #pragma unroll
            for (int d=1; d<64; d<<=1){
                int n = __shfl_up(incl, d);
                if ((tid & 63) >= d) incl += n;
            }
            offS[tid] = incl - v;
            if ((tid & 63) == 63) wsum4[tid>>6] = incl;
        }
        __syncthreads();
        {
            int w = tid >> 6, base = 0;
            #pragma unroll
            for (int i=0;i<4;i++) if (i < w) base += wsum4[i];
            offS[tid] += base;
        }
        __syncthreads();
        #pragma unroll
        for (int si=0; si<4; si++){
            if (mykey[si]){
                int s = si*256 + tid;
                int pos = offS[myc[si]] + myp[si];
                memS[pos] = s;
                kmem[b*SEQQ + pos] = s;
            }
        }
        kcnt[b*256 + tid] = cntS[tid];
        koff[b*256 + tid] = offS[tid];
        __syncthreads();     // memS visible to all
        // per-query padded member rows
        #pragma unroll
        for (int si=0; si<4; si++){
            int s = si*256 + tid;
            if (myc[si] >= 0){
                int c = myc[si];
                int cnt = cntS[c], off = offS[c];
                pcnt[b*SEQQ + s] = cnt;
                poff[b*SEQQ + s] = b*SEQQ + off;
                int mrow[16];
                #pragma unroll
                for (int j=0;j<16;j++)
                    mrow[j] = (j < cnt) ? memS[off + j] : s;   // pad with self (safe addr)
                int4* prow = (int4*)&pmem[(size_t)(b*SEQQ + s)*16];
                prow[0] = (int4){mrow[0], mrow[1], mrow[2], mrow[3]};
                prow[1] = (int4){mrow[4], mrow[5], mrow[6], mrow[7]};
                prow[2] = (int4){mrow[8], mrow[9], mrow[10],mrow[11]};
                prow[3] = (int4){mrow[12],mrow[13],mrow[14],mrow[15]};
            }
        }
        // zero the 769 outputs of this batch (head uses atomicAdd)
        #pragma unroll
        for (int si=0; si<4; si++){
            int idx = si*256 + tid;
            if (idx < 769) outz[b*769 + idx] = 0.f;
        }
    } else {
        // ---- embed + LN1(layer0): wave per row
        int row = (bid - 2312)*4 + (tid>>6);
        int lane = tid & 63;
        int b = row >> 10, s = row & 1023;
        int col = lane*4;
        float4 out;
        if (s == 0){
            float v = num_step[b]; out = (float4){v,v,v,v};
        } else if (s == SEQQ-1){
            out = (float4){-1.f,-1.f,-1.f,-1.f};
        } else {
            const float* in; const float* W; const float* bias;
            if (s <= NUM_PM){ in = pm_states + (size_t)(b*NUM_PM + s-1)*16; W = pm_W; bias = pm_b; }
            else            { in = vm_states + (size_t)(b*NUM_VM + (s-1-NUM_PM))*16; W = vm_W; bias = vm_b; }
            float4 i0 = *(const float4*)in,      i1 = *(const float4*)(in+4);
            float4 i2 = *(const float4*)(in+8),  i3 = *(const float4*)(in+12);
            float in16[16] = {i0.x,i0.y,i0.z,i0.w, i1.x,i1.y,i1.z,i1.w,
                              i2.x,i2.y,i2.z,i2.w, i3.x,i3.y,i3.z,i3.w};
            out = *(const float4*)&bias[col];
            #pragma unroll
            for (int k=0;k<16;k++){
                float4 w4 = *(const float4*)&W[k*DD + col];
                out.x = fmaf(in16[k], w4.x, out.x);
                out.y = fmaf(in16[k], w4.y, out.y);
                out.z = fmaf(in16[k], w4.z, out.z);
                out.w = fmaf(in16[k], w4.w, out.w);
            }
        }
        *(float4*)&x[(size_t)row*DD + col] = out;
        float s1 = out.x+out.y+out.z+out.w;
        float s2 = fmaf(out.x,out.x, fmaf(out.y,out.y, fmaf(out.z,out.z, out.w*out.w)));
        #pragma unroll
        for (int off=1; off<64; off<<=1){ s1 += __shfl_xor(s1,off); s2 += __shfl_xor(s2,off); }
        float m    = s1*(1.0f/DD);
        float var  = s2*(1.0f/DD) - m*m;
        float rstd = rsqrtf(var + 1e-5f);
        float4 g4 = *(const float4*)&g[col];
        float4 b4 = *(const float4*)&beta[col];
        short4 o;
        o.x = (short)f2bf((out.x-m)*rstd*g4.x + b4.x);
        o.y = (short)f2bf((out.y-m)*rstd*g4.y + b4.y);
        o.z = (short)f2bf((out.z-m)*rstd*g4.z + b4.z);
        o.w = (short)f2bf((out.w-m)*rstd*g4.w + b4.w);
        *(short4*)&h[(size_t)row*DD + col] = o;
    }
}

// ---------------------------------------------------------------- layernorm: wave per row, f32 in -> bf16 out
__global__ void ln_kernel(const float* __restrict__ x, const float* __restrict__ g,
                          const float* __restrict__ bta, u16* __restrict__ out)
{
    int row = blockIdx.x*4 + (threadIdx.x>>6);
    int lane = threadIdx.x & 63;
    const float4 v = *(const float4*)&x[(size_t)row*DD + lane*4];
    float s1 = v.x+v.y+v.z+v.w;
    float s2 = fmaf(v.x,v.x, fmaf(v.y,v.y, fmaf(v.z,v.z, v.w*v.w)));
    #pragma unroll
    for (int off=1; off<64; off<<=1){ s1 += __shfl_xor(s1,off); s2 += __shfl_xor(s2,off); }
    float m    = s1*(1.0f/DD);
    float var  = s2*(1.0f/DD) - m*m;
    float rstd = rsqrtf(var + 1e-5f);
    float4 g4 = *(const float4*)&g[lane*4];
    float4 b4 = *(const float4*)&bta[lane*4];
    short4 o;
    o.x = (short)f2bf((v.x-m)*rstd*g4.x + b4.x);
    o.y = (short)f2bf((v.y-m)*rstd*g4.y + b4.y);
    o.z = (short)f2bf((v.z-m)*rstd*g4.z + b4.z);
    o.w = (short)f2bf((v.w-m)*rstd*g4.w + b4.w);
    *(short4*)&out[(size_t)row*DD + lane*4] = o;
}

// T4 counted-vmcnt waits: keep prefetched tiles in flight across the barrier.
#define VMWAIT(N) asm volatile("s_waitcnt vmcnt(" #N ")" ::: "memory")

// ---------------------------------------------------------------- MFMA GEMM 64x128, 3-buf counted-vmcnt
// EPI: 0 = bias (QKV) ; 2 = bias+gelu (FF1)
template<int EPI>
__launch_bounds__(256)
__global__ void qgemm_kernel(const u16* __restrict__ A, const u16* __restrict__ Bt,
                             const float* __restrict__ bias, u16* __restrict__ C,
                             int N, int K)
{
    __shared__ u16 As[3][64][32];
    __shared__ u16 Bs[3][128][32];
    int tid = threadIdx.x;
    int wid = tid >> 6, lane = tid & 63;
    int wr = wid >> 1, wc = wid & 1;            // wave tile 32x64
    int row0 = blockIdx.y*64, col0 = blockIdx.x*128;
    int l15 = lane & 15, lh = lane >> 4;

    const u16* Ag = A  + (size_t)(row0 + wid*16 + (lane>>2))*K + (lane&3)*8;
    const u16* Bg = Bt + (size_t)(col0 + wid*32 + (lane>>2))*K + (lane&3)*8;

#define STAGE_Q(buf, k0) do{ \
    GLOAD16(Ag + (k0),          &As[buf][wid*16][0]);    \
    GLOAD16(Bg + (k0),          &Bs[buf][wid*32][0]);    \
    GLOAD16(Bg + (k0) + 16*K,   &Bs[buf][wid*32+16][0]); }while(0)

    f32x4 acc[2][4] = {};
    int nk = K >> 5;
    STAGE_Q(0, 0);
    STAGE_Q(1, 32);
    for (int kt = 0; kt < nk; kt++){
        int cur = kt % 3;
        if (kt+1 < nk) VMWAIT(3);   // oldest tile done; next tile's 3 loads stay in flight
        else           VMWAIT(0);
        __builtin_amdgcn_s_barrier();
        bf16x8 af[2], bfv[4];
        #pragma unroll
        for (int i=0;i<2;i++)
            af[i] = *(const bf16x8*)&As[cur][wr*32 + i*16 + l15][lh*8];
        #pragma unroll
        for (int j=0;j<4;j++)
            bfv[j] = *(const bf16x8*)&Bs[cur][wc*64 + j*16 + l15][lh*8];
        if (kt+2 < nk) STAGE_Q((kt+2)%3, (kt+2)*32);
        #pragma unroll
        for (int i=0;i<2;i++)
            #pragma unroll
            for (int j=0;j<4;j++)
                acc[i][j] = __builtin_amdgcn_mfma_f32_16x16x32_bf16(af[i], bfv[j], acc[i][j], 0,0,0);
    }
#undef STAGE_Q

    #pragma unroll
    for (int i=0;i<2;i++){
        #pragma unroll
        for (int j=0;j<4;j++){
            int col = col0 + wc*64 + j*16 + l15;
            float bb = bias[col];
            #pragma unroll
            for (int r=0;r<4;r++){
                int row = row0 + wr*32 + i*16 + lh*4 + r;
                float v = acc[i][j][r] + bb;
                if (EPI==2) v = gelu_tanh(v);
                C[(size_t)row*N + col] = f2bf(v);
            }
        }
    }
}

// ---------------------------------------------------------------- MFMA GEMM 32x64, 3-buf counted-vmcnt: x[M,256] += A@Bt^T + bias (+head)
// 4 waves, wave tile 16x32; waves 0-1 stage A (2 loads/tile), waves 2-3 stage B only (1 load/tile)
template<int HEAD>
__launch_bounds__(256)
__global__ void mgemm64_kernel(const u16* __restrict__ A, const u16* __restrict__ Bt,
                               const float* __restrict__ bias, float* __restrict__ x,
                               const float* __restrict__ out_W, const float* __restrict__ out_b,
                               const float* __restrict__ crit_W, const float* __restrict__ crit_b,
                               float* __restrict__ out, int K)
{
    __shared__ u16 As[3][32][32];
    __shared__ u16 Bs[3][64][32];
    int tid = threadIdx.x;
    int wid = tid >> 6, lane = tid & 63;
    int wr = wid >> 1, wc = wid & 1;            // wave tile 16x32
    int row0 = blockIdx.y*32, col0 = blockIdx.x*64;
    int l15 = lane & 15, lh = lane >> 4;

    const u16* Ag = A  + (size_t)(row0 + wid*16 + (lane>>2))*K + (lane&3)*8;   // used only by wid<2
    const u16* Bg = Bt + (size_t)(col0 + wid*16 + (lane>>2))*K + (lane&3)*8;

#define STAGE_S(buf, k0) do{ \
    if (wid < 2) GLOAD16(Ag + (k0), &As[buf][wid*16][0]); \
    GLOAD16(Bg + (k0), &Bs[buf][wid*16][0]); }while(0)

    f32x4 acc[2] = {};
    int nk = K >> 5;
    STAGE_S(0, 0);
    STAGE_S(1, 32);
    for (int kt = 0; kt < nk; kt++){
        int cur = kt % 3;
        if (kt+1 < nk){
            if (wid < 2) VMWAIT(2);   // per-wave counts differ: waves 0-1 issue 2 loads/tile
            else         VMWAIT(1);   // waves 2-3 issue 1 load/tile
        } else VMWAIT(0);
        __builtin_amdgcn_s_barrier();
        bf16x8 af, bfv[2];
        af = *(const bf16x8*)&As[cur][wr*16 + l15][lh*8];
        bfv[0] = *(const bf16x8*)&Bs[cur][wc*32 + l15][lh*8];
        bfv[1] = *(const bf16x8*)&Bs[cur][wc*32 + 16 + l15][lh*8];
        if (kt+2 < nk) STAGE_S((kt+2)%3, (kt+2)*32);
        acc[0] = __builtin_amdgcn_mfma_f32_16x16x32_bf16(af, bfv[0], acc[0], 0,0,0);
        acc[1] = __builtin_amdgcn_mfma_f32_16x16x32_bf16(af, bfv[1], acc[1], 0,0,0);
    }
#undef STAGE_S

    #pragma unroll
    for (int r=0;r<4;r++){
        int row = row0 + wr*16 + lh*4 + r;
        int s = row & 1023;
        float hp = 0.f;
        #pragma unroll
        for (int j=0;j<2;j++){
            int col = col0 + wc*32 + j*16 + l15;
            size_t idx = (size_t)row*DD + col;
            float v = acc[j][r] + bias[col] + x[idx];
            x[idx] = v;
            if (HEAD){
                float w = (s == 1023) ? crit_W[col] : out_W[col];
                hp = fmaf(v, w, hp);
            }
        }
        if (HEAD && s >= 1 + NUM_PM){
            hp += __shfl_xor(hp, 1);
            hp += __shfl_xor(hp, 2);
            hp += __shfl_xor(hp, 4);
            hp += __shfl_xor(hp, 8);
            if (l15 == 0){
                int b = row >> 10;
                int jj = (s == 1023) ? 768 : (s - (1 + NUM_PM));
                float add = hp;
                if (blockIdx.x == 0 && wc == 0)
                    add += (s == 1023) ? crit_b[0] : out_b[0];
                atomicAdd(&out[b*769 + jj], add);
            }
        }
    }
}

// ---------------------------------------------------------------- attention: wave per query; flat softmax fast path (cnt<=8)
__launch_bounds__(256)
__global__ void attn_kernel(const u16* __restrict__ qkv,
                            const int* __restrict__ pcnt, const int* __restrict__ pmem,
                            const int* __restrict__ poff, const int* __restrict__ kmem,
                            u16* __restrict__ o)
{
    int gq = blockIdx.x*4 + (threadIdx.x >> 6);
    int lane = threadIdx.x & 63;
    int b = gq >> 10, s = gq & 1023;
    const float scale = 0.17677669529663687f;       // 1/sqrt(32)

    if (s == 0 || s == SEQQ-1){
        const u16* vrow = qkv + (size_t)gq*768 + 512 + lane*4;
        *(short4*)(o + (size_t)gq*DD + lane*4) = *(const short4*)vrow;
        return;
    }

    const u16* qb = qkv + (size_t)gq*768 + lane*4;
    short4 q4i = *(const short4*)qb;
    float qx = bf2f((u16)q4i.x)*scale, qy = bf2f((u16)q4i.y)*scale,
          qz = bf2f((u16)q4i.z)*scale, qw = bf2f((u16)q4i.w)*scale;

    int cnt = pcnt[gq];
    const int4* prow = (const int4*)&pmem[(size_t)gq*16];
    int4 m0 = prow[0], m1 = prow[1];

    float l_run = 0.f;
    float ax=0.f, ay=0.f, az=0.f, aw=0.f;

    if (cnt <= 8){
        // ---- flat softmax: batch all loads (1 L2 round trip), no serial rescale chain
        short4 k4[8], v4[8];
#define LKV(J, MI) do{ const u16* kb_ = qkv + (size_t)(b*SEQQ + (MI))*768 + 256 + lane*4; \
        k4[J] = *(const short4*)kb_; v4[J] = *(const short4*)(kb_ + 256); }while(0)
        LKV(0, m0.x); LKV(1, m0.y); LKV(2, m0.z); LKV(3, m0.w);
        LKV(4, m1.x); LKV(5, m1.y); LKV(6, m1.z); LKV(7, m1.w);
#undef LKV
        float sc[8];
        #pragma unroll
        for (int j=0;j<8;j++){
            float d = qx*bf2f((u16)k4[j].x) + qy*bf2f((u16)k4[j].y)
                    + qz*bf2f((u16)k4[j].z) + qw*bf2f((u16)k4[j].w);
            d += __shfl_xor(d, 1);
            d += __shfl_xor(d, 2);
            d += __shfl_xor(d, 4);
            sc[j] = d;
        }
        float mx = -1e30f;
        #pragma unroll
        for (int j=0;j<8;j++) if (j < cnt) mx = fmaxf(mx, sc[j]);
        #pragma unroll
        for (int j=0;j<8;j++){
            if (j < cnt){
                float p = __expf(sc[j] - mx);
                l_run += p;
                ax = fmaf(p, bf2f((u16)v4[j].x), ax);
                ay = fmaf(p, bf2f((u16)v4[j].y), ay);
                az = fmaf(p, bf2f((u16)v4[j].z), az);
                aw = fmaf(p, bf2f((u16)v4[j].w), aw);
            }
        }
    } else {
        int4 m2 = prow[2], m3 = prow[3];
        float m_run = -1e30f;

#define ACHUNK(BASE, MV) do{                                              \
    if ((BASE) < cnt){                                                    \
        short4 k4[4], v4[4];                                              \
        const int mi0=(MV).x, mi1=(MV).y, mi2=(MV).z, mi3=(MV).w;         \
        const u16* kb0 = qkv + (size_t)(b*SEQQ + mi0)*768 + 256 + lane*4; \
        const u16* kb1 = qkv + (size_t)(b*SEQQ + mi1)*768 + 256 + lane*4; \
        const u16* kb2 = qkv + (size_t)(b*SEQQ + mi2)*768 + 256 + lane*4; \
        const u16* kb3 = qkv + (size_t)(b*SEQQ + mi3)*768 + 256 + lane*4; \
        k4[0]=*(const short4*)kb0; v4[0]=*(const short4*)(kb0+256);       \
        k4[1]=*(const short4*)kb1; v4[1]=*(const short4*)(kb1+256);       \
        k4[2]=*(const short4*)kb2; v4[2]=*(const short4*)(kb2+256);       \
        k4[3]=*(const short4*)kb3; v4[3]=*(const short4*)(kb3+256);       \
        _Pragma("unroll")                                                 \
        for (int k=0;k<4;k++){                                            \
            if ((BASE) + k < cnt){                                        \
                float sc = qx*bf2f((u16)k4[k].x) + qy*bf2f((u16)k4[k].y)  \
                         + qz*bf2f((u16)k4[k].z) + qw*bf2f((u16)k4[k].w); \
                sc += __shfl_xor(sc, 1);                                  \
                sc += __shfl_xor(sc, 2);                                  \
                sc += __shfl_xor(sc, 4);                                  \
                float mn = fmaxf(m_run, sc);                              \
                float corr = __expf(m_run - mn);                          \
                float p = __expf(sc - mn);                                \
                l_run = l_run*corr + p;                                   \
                ax = ax*corr + p*bf2f((u16)v4[k].x);                      \
                ay = ay*corr + p*bf2f((u16)v4[k].y);                      \
                az = az*corr + p*bf2f((u16)v4[k].z);                      \
                aw = aw*corr + p*bf2f((u16)v4[k].w);                      \
                m_run = mn;                                               \
            }                                                             \
        }                                                                 \
    } }while(0)

        if (cnt <= 16){
            ACHUNK(0,  m0);
            ACHUNK(4,  m1);
            ACHUNK(8,  m2);
            ACHUNK(12, m3);
        } else {
            const int* klist = kmem + poff[gq];
            for (int j0 = 0; j0 < cnt; j0 += 4){
                short4 k4[4], v4[4];
                #pragma unroll
                for (int k=0;k<4;k++){
                    int jj = j0 + k; jj = (jj < cnt) ? jj : (cnt-1);
                    int mi = klist[jj];
                    const u16* kb = qkv + (size_t)(b*SEQQ + mi)*768 + 256 + lane*4;
                    k4[k] = *(const short4*)kb;
                    v4[k] = *(const short4*)(kb + 256);
                }
                #pragma unroll
                for (int k=0;k<4;k++){
                    if (j0 + k < cnt){
                        float sc = qx*bf2f((u16)k4[k].x) + qy*bf2f((u16)k4[k].y)
                                 + qz*bf2f((u16)k4[k].z) + qw*bf2f((u16)k4[k].w);
                        sc += __shfl_xor(sc, 1);
                        sc += __shfl_xor(sc, 2);
                        sc += __shfl_xor(sc, 4);
                        float mn = fmaxf(m_run, sc);
                        float corr = __expf(m_run - mn);
                        float p = __expf(sc - mn);
                        l_run = l_run*corr + p;
                        ax = ax*corr + p*bf2f((u16)v4[k].x);
                        ay = ay*corr + p*bf2f((u16)v4[k].y);
                        az = az*corr + p*bf2f((u16)v4[k].z);
                        aw = aw*corr + p*bf2f((u16)v4[k].w);
                        m_run = mn;
                    }
                }
            }
        }
#undef ACHUNK
    }

    float inv = (l_run > 0.f) ? 1.0f/l_run : 0.f;
    u16* orow = o + (size_t)gq*DD + lane*4;
    short4 outv;
    outv.x = (short)f2bf(ax*inv); outv.y = (short)f2bf(ay*inv);
    outv.z = (short)f2bf(az*inv); outv.w = (short)f2bf(aw*inv);
    *(short4*)orow = outv;
}

// ---------------------------------------------------------------- launch
extern "C" void kernel_launch(void* const* d_in, const int* in_sizes, int n_in,
                              void* d_out, int out_size, void* d_ws, size_t ws_size,
                              hipStream_t stream)
{
    const float* vm_states = (const float*)d_in[0];
    const float* num_step  = (const float*)d_in[1];
    const float* pm_states = (const float*)d_in[2];
    const int*   rel       = (const int*)d_in[3];
    const unsigned char* mask = (const unsigned char*)d_in[4];
    const float* pm_W = (const float*)d_in[5];
    const float* pm_b = (const float*)d_in[6];
    const float* vm_W = (const float*)d_in[7];
    const float* vm_b = (const float*)d_in[8];
    const float* Wqkv = (const float*)d_in[9];
    const float* bqkv = (const float*)d_in[10];
    const float* Wo   = (const float*)d_in[11];
    const float* bo   = (const float*)d_in[12];
    const float* ln1g = (const float*)d_in[13];
    const float* ln1b = (const float*)d_in[14];
    const float* ln2g = (const float*)d_in[15];
    const float* ln2b = (const float*)d_in[16];
    const float* W1   = (const float*)d_in[17];
    const float* b1   = (const float*)d_in[18];
    const float* W2   = (const float*)d_in[19];
    const float* b2   = (const float*)d_in[20];
    const float* out_W = (const float*)d_in[21];
    const float* out_b = (const float*)d_in[22];
    const float* crit_W = (const float*)d_in[23];
    const float* crit_b = (const float*)d_in[24];

    char* ws = (char*)d_ws;
    const size_t MB = 1024*1024;
    float* x    = (float*)(ws);                      // [8192][256] f32   :  0..8 MB
    u16*   hbuf = (u16*)(ws + 8*MB);                 // [8192][256] bf16  :  8..12
    u16*   aout = (u16*)(ws + 12*MB);                // [8192][256] bf16  : 12..16
    u16*   qkv  = (u16*)(ws + 16*MB);                // [8192][768] bf16  : 16..28
    u16*   ff1  = (u16*)(ws + 28*MB);                // [8192][1024] bf16 : 28..44
    u16*   wq   = (u16*)(ws + 44*MB);                // [3][768][256]
    u16*   wo   = wq + (size_t)3*768*256;            // [3][256][256]
    u16*   w1   = wo + (size_t)3*256*256;            // [3][1024][256]
    u16*   w2   = w1 + (size_t)3*1024*256;           // [3][256][1024]
    int*   kcnt = (int*)(ws + 50*MB);                // [8][256]
    int*   koff = kcnt + NB*256;                     // [8][256]
    int*   kmem = koff + NB*256;                     // [8][1024]
    int*   pcnt = kmem + NB*SEQQ;                    // [8192]
    int*   poff = pcnt + MROWS;                      // [8192]
    int*   pmem = poff + MROWS;                      // [8192][16]

    prologue_kernel<<<4360, 256, 0, stream>>>(Wqkv, Wo, W1, W2, wq, wo, w1, w2,
                                              rel, mask, kcnt, koff, kmem, pcnt, poff, pmem,
                                              vm_states, num_step, pm_states,
                                              pm_W, pm_b, vm_W, vm_b,
                                              ln1g, ln1b, x, hbuf, (float*)d_out);
    for (int i=0;i<3;i++){
        qgemm_kernel<0><<<dim3(768/128, MROWS/64),256,0,stream>>>(
            hbuf, wq + (size_t)i*768*256, bqkv + i*768, qkv, 768, 256);
        attn_kernel<<<MROWS/4, 256, 0, stream>>>(qkv, pcnt, pmem, poff, kmem, aout);
        mgemm64_kernel<0><<<dim3(256/64, MROWS/32),256,0,stream>>>(
            aout, wo + (size_t)i*256*256, bo + i*DD, x,
            nullptr, nullptr, nullptr, nullptr, nullptr, 256);
        ln_kernel<<<MROWS/4,256,0,stream>>>(x, ln2g + i*DD, ln2b + i*DD, hbuf);
        qgemm_kernel<2><<<dim3(1024/128, MROWS/64),256,0,stream>>>(
            hbuf, w1 + (size_t)i*1024*256, b1 + i*FF, ff1, 1024, 256);
        if (i < 2){
            mgemm64_kernel<0><<<dim3(256/64, MROWS/32),256,0,stream>>>(
                ff1, w2 + (size_t)i*256*1024, b2 + i*DD, x,
                nullptr, nullptr, nullptr, nullptr, nullptr, 1024);
            ln_kernel<<<MROWS/4,256,0,stream>>>(x, ln1g + (i+1)*DD, ln1b + (i+1)*DD, hbuf);
        } else {
            mgemm64_kernel<1><<<dim3(256/64, MROWS/32),256,0,stream>>>(
                ff1, w2 + (size_t)i*256*1024, b2 + i*DD, x,
                out_W, out_b, crit_W, crit_b, (float*)d_out, 1024);
        }
    }
}